// Round 5
// baseline (560.401 us; speedup 1.0000x reference)
//
#include <hip/hip_runtime.h>
#include <hip/hip_bf16.h>

#define NN 10000
#define EE 160000
#define DD 128
#define HH 4
#define CC 32
#define FFF 512
#define LL 2
#define RELV 100
#define EPS 1e-6f
#define GATE_BIAS 3.0f
#define BM 32
#define NT 16

typedef __bf16 bf16x8 __attribute__((ext_vector_type(8)));
typedef float f32x4 __attribute__((ext_vector_type(4)));
typedef float f32x16 __attribute__((ext_vector_type(16)));

#define MFMA(a,b,c)   __builtin_amdgcn_mfma_f32_16x16x32_bf16((a),(b),(c),0,0,0)
#define MFMA32(a,b,c) __builtin_amdgcn_mfma_f32_32x32x16_bf16((a),(b),(c),0,0,0)

__device__ __forceinline__ int swzK(int e, int b){ return e*256 + (b ^ ((e&7)<<4)); }   // [R][128] bf16
__device__ __forceinline__ int swz128(int e, int b){ return e*256 + (b ^ ((e&7)<<4)); } // [16][128] bf16
__device__ __forceinline__ int swz512(int e, int b){ return e*1024 + (b ^ ((e&7)<<4)); }// [16][512] bf16

__global__ __launch_bounds__(128) void k_gx(
    const int* __restrict__ node_ids, const float* __restrict__ node_emb,
    float* __restrict__ x, ushort* __restrict__ xb){
  int n = blockIdx.x, t = threadIdx.x;
  float v = node_emb[(long)node_ids[n]*DD + t];
  x[(long)n*DD + t] = v;
  __hip_bfloat16 h = __float2bfloat16(v);
  xb[(long)n*DD + t] = *(ushort*)&h;
}

__global__ __launch_bounds__(256) void k_f2b(const float* __restrict__ in, ushort* __restrict__ out, long n){
  long i = (long)blockIdx.x*256 + threadIdx.x;
  if (i < n){
    __hip_bfloat16 h = __float2bfloat16(in[i]);
    out[i] = *(ushort*)&h;
  }
}

__global__ __launch_bounds__(256) void k_subcast(
    const float* __restrict__ in, ushort* __restrict__ out, int OUT, int IN, int instride, int off){
  long tid = (long)blockIdx.x*256 + threadIdx.x;
  if (tid >= (long)OUT*IN) return;
  int o = tid / IN, i = tid % IN;
  __hip_bfloat16 h = __float2bfloat16(in[(long)o*instride + off + i]);
  out[tid] = *(ushort*)&h;
}

// W[OUT][instride] fp32 (cols off..off+IN) -> MFMA32 fragment order bf16
__global__ __launch_bounds__(256) void k_wprep(
    const float* __restrict__ in, ushort* __restrict__ out, int OUT, int IN, int instride, int off){
  int tid = blockIdx.x*256 + threadIdx.x;
  int total = OUT*IN/8;
  if (tid >= total) return;
  int lane = tid & 63;
  int grp  = tid >> 6;
  int nkb  = IN >> 4;
  int kb   = grp % nkb;
  int cb   = grp / nkb;
  int col  = cb*32 + (lane & 31);
  int k0   = kb*16 + (lane >> 5)*8;
  const float* p = in + (long)col*instride + off + k0;
  bf16x8 h;
  #pragma unroll
  for (int j=0;j<8;++j) h[j] = (__bf16)p[j];
  *(bf16x8*)(out + (long)tid*8) = h;
}

// per-relation precompute: EA2[rel][f] = bf16(emb@Aw2^T + Ab), EK[rel][o] = emb@Kw2^T (fp32)
__global__ __launch_bounds__(256) void k_ea(
    const float* __restrict__ edge_emb, const float* __restrict__ relA_w,
    const float* __restrict__ relA_b, const float* __restrict__ k_w,
    ushort* __restrict__ EA2b, float* __restrict__ EKf){
  int rel = blockIdx.x, t = threadIdx.x;
  __shared__ float emb[128];
  if (t < 128) emb[t] = edge_emb[(long)rel*DD + t];
  __syncthreads();
  for (int f=t; f<FFF; f+=256){
    const float* wr = relA_w + (long)f*256 + 128;
    float s = relA_b[f];
    for (int i=0;i<128;++i) s += emb[i]*wr[i];
    __hip_bfloat16 h = __float2bfloat16(s);
    EA2b[(long)rel*FFF + f] = *(ushort*)&h;
  }
  if (t < 128){
    const float* wr = k_w + (long)t*256 + 128;
    float s = 0.f;
    for (int i=0;i<128;++i) s += emb[i]*wr[i];
    EKf[(long)rel*DD + t] = s;
  }
}

__global__ __launch_bounds__(256) void k_init(float* __restrict__ denom, float* __restrict__ agg){
  int i = blockIdx.x*256 + threadIdx.x;
  if (i < NN*DD) agg[i] = 0.f;
  if (i < NN*HH) denom[i] = 0.f;
}

// ---- dst-sort: hist -> scan -> scatter (once per call) ----
__global__ __launch_bounds__(256) void k_zeroh(int* __restrict__ hist){
  int i = blockIdx.x*256 + threadIdx.x;
  if (i < NN) hist[i] = 0;
}
__global__ __launch_bounds__(256) void k_hist(const int* __restrict__ dst, int* __restrict__ hist){
  int e = blockIdx.x*256 + threadIdx.x;
  if (e < EE) atomicAdd(&hist[dst[e]], 1);
}
// exclusive prefix of hist[NN] -> cursor[NN]; single block, 256 threads
__global__ __launch_bounds__(256) void k_scan(const int* __restrict__ hist, int* __restrict__ cursor){
  __shared__ int tsum[256];
  const int t = threadIdx.x;
  const int PER = (NN + 255) / 256;   // 40
  const int base = t*PER;
  int s = 0;
  for (int i=0;i<PER;++i){ int idx = base+i; if (idx < NN) s += hist[idx]; }
  tsum[t] = s;
  __syncthreads();
  if (t == 0){
    int run = 0;
    for (int i=0;i<256;++i){ int v = tsum[i]; tsum[i] = run; run += v; }
  }
  __syncthreads();
  int run = tsum[t];
  for (int i=0;i<PER;++i){
    int idx = base+i;
    if (idx < NN){ int v = hist[idx]; cursor[idx] = run; run += v; }
  }
}
__global__ __launch_bounds__(256) void k_scatter(const int* __restrict__ dst,
    int* __restrict__ cursor, int* __restrict__ perm){
  int e = blockIdx.x*256 + threadIdx.x;
  if (e < EE){
    int p = atomicAdd(&cursor[dst[e]], 1);
    perm[p] = e;
  }
}

// fused LN+q-proj AND XA = x@Aw1^T. 16 nodes/block, 4 waves.
__global__ __launch_bounds__(256) void k_lnq_xa(
    const float* __restrict__ x, const float* __restrict__ lnw, const float* __restrict__ lnb,
    const ushort* __restrict__ qwb, const ushort* __restrict__ a1b,
    float* __restrict__ q, ushort* __restrict__ XAb){
  __shared__ __align__(16) unsigned char HB[NT*256];    // LN'd x (bf16)
  __shared__ __align__(16) unsigned char HR[NT*256];    // raw x (bf16)
  const int n0 = blockIdx.x*NT;
  const int t = threadIdx.x;
  const int e = t>>4, s = t&15;
  const int w = t>>6, l = t&63, lr = l&15, lg = l>>4;
  {
    const float* xp = x + (long)(n0+e)*DD + s*8;
    float xv[8];
    *(float4*)&xv[0] = *(const float4*)xp;
    *(float4*)&xv[4] = *(const float4*)(xp+4);
    float sm = 0.f;
    #pragma unroll
    for (int i=0;i<8;++i) sm += xv[i];
    sm += __shfl_xor(sm,1); sm += __shfl_xor(sm,2);
    sm += __shfl_xor(sm,4); sm += __shfl_xor(sm,8);
    float mu = sm*(1.f/DD);
    float sq = 0.f;
    #pragma unroll
    for (int i=0;i<8;++i){ float d = xv[i]-mu; sq += d*d; }
    sq += __shfl_xor(sq,1); sq += __shfl_xor(sq,2);
    sq += __shfl_xor(sq,4); sq += __shfl_xor(sq,8);
    float rstd = rsqrtf(sq*(1.f/DD) + EPS);
    float4 w0 = *(const float4*)(lnw + s*8), w1 = *(const float4*)(lnw + s*8 + 4);
    float4 b0 = *(const float4*)(lnb + s*8), b1 = *(const float4*)(lnb + s*8 + 4);
    float wv[8] = {w0.x,w0.y,w0.z,w0.w,w1.x,w1.y,w1.z,w1.w};
    float bv[8] = {b0.x,b0.y,b0.z,b0.w,b1.x,b1.y,b1.z,b1.w};
    bf16x8 hb, hr;
    #pragma unroll
    for (int i=0;i<8;++i){
      hb[i] = (__bf16)((xv[i]-mu)*rstd*wv[i] + bv[i]);
      hr[i] = (__bf16)xv[i];
    }
    *(bf16x8*)(HB + swz128(e, s*16)) = hb;
    *(bf16x8*)(HR + swz128(e, s*16)) = hr;
  }
  __syncthreads();
  // q projection (K=128) from HB
  {
    const int o0 = w*32;
    f32x4 z = {0.f,0.f,0.f,0.f};
    f32x4 acc[2] = {z,z};
    #pragma unroll
    for (int k4=0;k4<4;++k4){
      bf16x8 a = *(const bf16x8*)(HB + swz128(lr, k4*64 + lg*16));
      #pragma unroll
      for (int nt=0;nt<2;++nt){
        bf16x8 b = *(const bf16x8*)(qwb + (long)(o0+nt*16+lr)*128 + k4*32 + lg*8);
        acc[nt] = MFMA(a, b, acc[nt]);
      }
    }
    #pragma unroll
    for (int nt=0;nt<2;++nt)
      #pragma unroll
      for (int r=0;r<4;++r)
        q[(long)(n0 + lg*4 + r)*DD + o0 + nt*16 + lr] = acc[nt][r];
  }
  // XA (512 out, K=128) from HR
  {
    const int f0w = w*128;
    f32x4 z = {0.f,0.f,0.f,0.f};
    f32x4 acc[8] = {z,z,z,z,z,z,z,z};
    #pragma unroll
    for (int k4=0;k4<4;++k4){
      bf16x8 a = *(const bf16x8*)(HR + swz128(lr, k4*64 + lg*16));
      #pragma unroll
      for (int nt=0;nt<8;++nt){
        bf16x8 b = *(const bf16x8*)(a1b + (long)(f0w+nt*16+lr)*128 + k4*32 + lg*8);
        acc[nt] = MFMA(a, b, acc[nt]);
      }
    }
    #pragma unroll
    for (int nt=0;nt<8;++nt)
      #pragma unroll
      for (int r=0;r<4;++r){
        __hip_bfloat16 h = __float2bfloat16(acc[nt][r]);
        XAb[(long)(n0+lg*4+r)*FFF + f0w+nt*16+lr] = *(ushort*)&h;
      }
  }
}

// --- fused edge kernel (dst-sorted): gather-celu + G/B/K/V MFMA32 + exp + LDS segment-reduce ---
// v6: BM 64 -> 32 at 512 threads. Occupancy was register-bound: acc share = BM*128*2*4/512
//     = 32 AGPR at BM=64 -> combined ~92 regs -> 2 blocks/CU (50%) no matter the LDS.
//     BM=32 halves acc to one f32x16 (16) -> combined ~76 -> 3 blocks/CU (75%), LDS ~17.4KB,
//     5000 blocks: more independent blocks to hide the barrier-chain latency.
__global__ __launch_bounds__(512,4) void k_edge(
    const ushort* __restrict__ xb, const ushort* __restrict__ XAb,
    const ushort* __restrict__ EAb, const float* __restrict__ EKf,
    const float* __restrict__ q,
    const int* __restrict__ src, const int* __restrict__ dst, const int* __restrict__ eids,
    const int* __restrict__ perm,
    const ushort* __restrict__ Gwb, const float* __restrict__ Gb,
    const ushort* __restrict__ Bwb, const float* __restrict__ Bb,
    const ushort* __restrict__ Kwb, const ushort* __restrict__ Vwb,
    float* __restrict__ agg, float* __restrict__ denom)
{
  __shared__ __align__(16) unsigned char KVB[BM*256];   // 8KB bf16 [32][128] swz; later AGB rows 0..15 (fp32 linear)
  __shared__ __align__(16) unsigned char INTB[BM*256];  // 8KB bf16 [32][128] swz (celu chunk / gate); later AGB rows 16..31
  __shared__ float EXL[BM][HH];                         // 512B: ex per (edge, head)
  __shared__ int srcl[BM], dstl[BM], eidl[BM];

  const int e0 = blockIdx.x * BM;
  const int t  = threadIdx.x;
  const int w  = t >> 6;
  const int l  = t & 63;
  const int c32 = l & 31;
  const int hi  = l >> 5;
  const bool isG = (w < 4);
  const int cbO = isG ? w : (w-4);
  const int oc  = cbO*32 + c32;

  if (t < BM){
    int pe = perm[e0+t];
    srcl[t] = src[pe]; dstl[t] = dst[pe]; eidl[t] = eids[pe];
  }
  __syncthreads();

  // stage kv_j = xb[src] into KVB (32 edges x 16 uint4 = 512 = one per thread)
  {
    const uint4* xbu = (const uint4*)xb;
    int e = t >> 4, qq = t & 15;
    *(uint4*)(KVB + swzK(e, qq*16)) = xbu[(long)srcl[e]*16 + qq];
  }

  f32x16 gb;
  {
    float b0 = isG ? (Gb[oc] + GATE_BIAS) : Bb[oc];
    #pragma unroll
    for (int i=0;i<16;++i) gb[i] = b0;
  }
  const ushort* GBw = isG ? Gwb : Bwb;

  // prologue: issue chunk-0 gather (one bf16x8 pair per thread)
  bf16x8 xa8, ea8;
  {
    int e = t >> 4, c8 = t & 15;
    xa8 = *(const bf16x8*)(XAb + (long)srcl[e]*FFF + c8*8);
    ea8 = *(const bf16x8*)(EAb + (long)eidl[e]*FFF + c8*8);
  }

  // 4 chunks of 128 cols, pipelined: GEMM(ch-1) while gather(ch) in flight
  #pragma unroll
  for (int ch=0; ch<4; ++ch){
    if (ch > 0){
      const ushort* Bp = GBw + ((long)(cbO*32 + (ch-1)*8)*64 + l)*8;
      bf16x8 wf[8];
      #pragma unroll
      for (int i=0;i<8;++i) wf[i] = *(const bf16x8*)(Bp + (long)i*512);
      #pragma unroll
      for (int i=0;i<8;++i){
        bf16x8 a = *(const bf16x8*)(INTB + swzK(c32, i*32 + hi*16));
        gb = MFMA32(a, wf[i], gb);
      }
    }
    // celu of current chunk
    bf16x8 o;
    #pragma unroll
    for (int j=0;j<8;++j){
      float s = (float)xa8[j] + (float)ea8[j];
      o[j] = (__bf16)((s > 0.f) ? s : (__expf(s) - 1.f));
    }
    __syncthreads();   // all waves done reading INTB(ch-1)
    {
      int e = t >> 4, c8 = t & 15;
      *(bf16x8*)(INTB + swzK(e, c8*16)) = o;
    }
    __syncthreads();   // INTB(ch) visible
    if (ch < 3){
      int e = t >> 4, c8 = t & 15;
      xa8 = *(const bf16x8*)(XAb + (long)srcl[e]*FFF + (ch+1)*128 + c8*8);
      ea8 = *(const bf16x8*)(EAb + (long)eidl[e]*FFF + (ch+1)*128 + c8*8);
    }
  }
  // epilogue: GEMM on the last chunk
  {
    const ushort* Bp = GBw + ((long)(cbO*32 + 3*8)*64 + l)*8;
    bf16x8 wf[8];
    #pragma unroll
    for (int i=0;i<8;++i) wf[i] = *(const bf16x8*)(Bp + (long)i*512);
    #pragma unroll
    for (int i=0;i<8;++i){
      bf16x8 a = *(const bf16x8*)(INTB + swzK(c32, i*32 + hi*16));
      gb = MFMA32(a, wf[i], gb);
    }
  }
  __syncthreads();   // last chunk MFMA done; INTB free for gate

  // G-waves: g = sigmoid(ga) into INTB
  if (isG){
    #pragma unroll
    for (int r=0;r<16;++r){
      int row = (r&3) + 8*(r>>2) + 4*hi;
      float g0 = 1.f/(1.f + __expf(-gb[r]));
      *(__bf16*)(INTB + swzK(row, oc*2)) = (__bf16)g0;
    }
  }
  __syncthreads();

  // B-waves: blend kv2 into KVB
  if (!isG){
    #pragma unroll
    for (int r=0;r<16;++r){
      int row = (r&3) + 8*(r>>2) + 4*hi;
      float g0 = (float)*(const __bf16*)(INTB + swzK(row, oc*2));
      float kv0 = (float)*(const __bf16*)(KVB + swzK(row, oc*2));
      float o0v = gb[r] + g0*(kv0 - gb[r]);
      *(__bf16*)(KVB + swzK(row, oc*2)) = (__bf16)o0v;
    }
  }
  __syncthreads();   // kv2 ready in KVB

  // all waves: GEMM vs kv2 (K=128).  G-waves -> k-preact (head w), B-waves -> v.
  f32x16 ra;
  #pragma unroll
  for (int i=0;i<16;++i) ra[i] = 0.f;
  {
    const ushort* Wp = (isG ? Kwb : Vwb) + ((long)cbO*8*64 + l)*8;
    bf16x8 wf[8];
    #pragma unroll
    for (int i=0;i<8;++i) wf[i] = *(const bf16x8*)(Wp + (long)i*512);
    #pragma unroll
    for (int i=0;i<8;++i){
      bf16x8 a = *(const bf16x8*)(KVB + swzK(c32, i*32 + hi*16));
      ra = MFMA32(a, wf[i], ra);
    }
  }
  __syncthreads();   // ALL KVB reads done; KVB+INTB become fp32 AGB[32][128] (linear)

  if (isG){
    // k += EK[eid]; score vs q[dst]; EXL = exp(score)
    #pragma unroll
    for (int r=0;r<16;++r){
      int row = (r&3) + 8*(r>>2) + 4*hi;
      int e = row, dn = dstl[e];
      float kv = ra[r] + EKf[(long)eidl[e]*DD + w*32 + c32];
      float p = kv * q[(long)dn*DD + w*32 + c32];
      p += __shfl_xor(p, 1); p += __shfl_xor(p, 2);
      p += __shfl_xor(p, 4); p += __shfl_xor(p, 8);
      p += __shfl_xor(p, 16);
      if (c32 == 0) EXL[e][w] = __expf(p);
    }
  } else {
    // write raw va into overlaid AGB: rows 0..15 -> KVB, rows 16..31 -> INTB (fp32 linear)
    #pragma unroll
    for (int r=0;r<16;++r){
      int row = (r&3) + 8*(r>>2) + 4*hi;
      unsigned char* ab = (row < 16) ? KVB : INTB;
      int lr2 = row & 15;
      *(float*)(ab + (lr2*128 + oc)*4) = ra[r];
    }
  }
  __syncthreads();   // EXL + AGB ready

  // segment-reduce (dst-sorted rows): 512 threads = 128 cols x 4 row-groups of 8
  {
    const int col = t & 127;
    const int rg  = t >> 7;
    const int r0  = rg*8;
    const int h   = col >> 5;
    const unsigned char* ab = (rg < 2) ? KVB : INTB;   // wave-uniform
    const int rb = (rg & 1) * 8;
    float acc = 0.f;
    int cur = dstl[r0];
    for (int r=0; r<8; ++r){
      int dn = dstl[r0+r];
      if (dn != cur){
        atomicAdd(&agg[(long)cur*DD + col], acc);
        acc = 0.f; cur = dn;
      }
      acc += *(const float*)(ab + ((rb + r)*128 + col)*4) * EXL[r0+r][h];
    }
    atomicAdd(&agg[(long)cur*DD + col], acc);
    if (col < HH){
      float da = 0.f; int cur2 = dstl[r0];
      for (int r=r0; r<r0+8; ++r){
        int dn = dstl[r];
        if (dn != cur2){
          atomicAdd(&denom[cur2*HH + col], da);
          da = 0.f; cur2 = dn;
        }
        da += EXL[r][col];
      }
      atomicAdd(&denom[cur2*HH + col], da);
    }
  }
}

// fused: x1 = x + (agg/denom)@o_w^T;  x = x1 + relu(LN(x1)@wi^T)@wo^T;  emits xb
__global__ __launch_bounds__(256) void k_node(
    const float* __restrict__ agg, const float* __restrict__ denom,
    const ushort* __restrict__ owb,
    const float* __restrict__ lnw, const float* __restrict__ lnb,
    const ushort* __restrict__ wib, const ushort* __restrict__ wob,
    float* __restrict__ x, ushort* __restrict__ xb){
  __shared__ __align__(16) unsigned char AB[NT*256];
  __shared__ __align__(16) unsigned char IB[NT*1024];
  __shared__ __align__(16) float XO[NT][132];
  const int n0 = blockIdx.x*NT;
  const int t = threadIdx.x;
  const int e = t>>4, s = t&15;
  const int w = t>>6, l = t&63, lr = l&15, lg = l>>4;

  {
    const float* ap = agg + (long)(n0+e)*DD + s*8;
    float av[8];
    *(float4*)&av[0] = *(const float4*)ap;
    *(float4*)&av[4] = *(const float4*)(ap+4);
    float dinv = 1.f / denom[(n0+e)*HH + (s>>2)];
    bf16x8 hb;
    #pragma unroll
    for (int i=0;i<8;++i) hb[i] = (__bf16)(av[i]*dinv);
    *(bf16x8*)(AB + swz128(e, s*16)) = hb;
  }
  __syncthreads();

  {
    const int o0 = w*32;
    f32x4 z = {0.f,0.f,0.f,0.f};
    f32x4 acc[2] = {z,z};
    #pragma unroll
    for (int k4=0;k4<4;++k4){
      bf16x8 a = *(const bf16x8*)(AB + swz128(lr, k4*64 + lg*16));
      #pragma unroll
      for (int nt=0;nt<2;++nt){
        bf16x8 b = *(const bf16x8*)(owb + (long)(o0+nt*16+lr)*128 + k4*32 + lg*8);
        acc[nt] = MFMA(a, b, acc[nt]);
      }
    }
    #pragma unroll
    for (int nt=0;nt<2;++nt)
      #pragma unroll
      for (int r=0;r<4;++r)
        XO[lg*4+r][o0+nt*16+lr] = acc[nt][r];
  }
  __syncthreads();

  float x1[8];
  {
    const float* xp = x + (long)(n0+e)*DD + s*8;
    float xv[8];
    *(float4*)&xv[0] = *(const float4*)xp;
    *(float4*)&xv[4] = *(const float4*)(xp+4);
    #pragma unroll
    for (int i=0;i<8;++i) x1[i] = xv[i] + XO[e][s*8+i];
    float sm = 0.f;
    #pragma unroll
    for (int i=0;i<8;++i) sm += x1[i];
    sm += __shfl_xor(sm,1); sm += __shfl_xor(sm,2);
    sm += __shfl_xor(sm,4); sm += __shfl_xor(sm,8);
    float mu = sm*(1.f/DD);
    float sq = 0.f;
    #pragma unroll
    for (int i=0;i<8;++i){ float d = x1[i]-mu; sq += d*d; }
    sq += __shfl_xor(sq,1); sq += __shfl_xor(sq,2);
    sq += __shfl_xor(sq,4); sq += __shfl_xor(sq,8);
    float rstd = rsqrtf(sq*(1.f/DD) + EPS);
    float4 w0 = *(const float4*)(lnw + s*8), w1 = *(const float4*)(lnw + s*8 + 4);
    float4 b0 = *(const float4*)(lnb + s*8), b1 = *(const float4*)(lnb + s*8 + 4);
    float wv[8] = {w0.x,w0.y,w0.z,w0.w,w1.x,w1.y,w1.z,w1.w};
    float bv[8] = {b0.x,b0.y,b0.z,b0.w,b1.x,b1.y,b1.z,b1.w};
    bf16x8 hb;
    #pragma unroll
    for (int i=0;i<8;++i) hb[i] = (__bf16)((x1[i]-mu)*rstd*wv[i] + bv[i]);
    __syncthreads();
    *(bf16x8*)(AB + swz128(e, s*16)) = hb;
  }
  __syncthreads();

  {
    const int f0w = w*128;
    f32x4 z = {0.f,0.f,0.f,0.f};
    f32x4 acc[8] = {z,z,z,z,z,z,z,z};
    #pragma unroll
    for (int k4=0;k4<4;++k4){
      bf16x8 a = *(const bf16x8*)(AB + swz128(lr, k4*64 + lg*16));
      #pragma unroll
      for (int nt=0;nt<8;++nt){
        bf16x8 b = *(const bf16x8*)(wib + (long)(f0w+nt*16+lr)*128 + k4*32 + lg*8);
        acc[nt] = MFMA(a, b, acc[nt]);
      }
    }
    #pragma unroll
    for (int nt=0;nt<8;++nt)
      #pragma unroll
      for (int r=0;r<4;++r){
        int e2 = lg*4 + r;
        int f = f0w + nt*16 + lr;
        float va = acc[nt][r];
        *(__bf16*)(IB + swz512(e2, f*2)) = (__bf16)fmaxf(va, 0.f);
      }
  }
  __syncthreads();

  {
    const int o0 = w*32;
    f32x4 z = {0.f,0.f,0.f,0.f};
    f32x4 acc[2] = {z,z};
    #pragma unroll
    for (int k16=0;k16<16;++k16){
      bf16x8 a = *(const bf16x8*)(IB + swz512(lr, k16*64 + lg*16));
      #pragma unroll
      for (int nt=0;nt<2;++nt){
        bf16x8 b = *(const bf16x8*)(wob + (long)(o0+nt*16+lr)*512 + k16*32 + lg*8);
        acc[nt] = MFMA(a, b, acc[nt]);
      }
    }
    #pragma unroll
    for (int nt=0;nt<2;++nt)
      #pragma unroll
      for (int r=0;r<4;++r)
        XO[lg*4+r][o0+nt*16+lr] = acc[nt][r];
  }
  __syncthreads();

  {
    float xn[8];
    #pragma unroll
    for (int i=0;i<8;++i) xn[i] = x1[i] + XO[e][s*8+i];
    float* xp = x + (long)(n0+e)*DD + s*8;
    *(float4*)xp = *(float4*)&xn[0];
    *(float4*)(xp+4) = *(float4*)&xn[4];
    bf16x8 hb;
    #pragma unroll
    for (int i=0;i<8;++i) hb[i] = (__bf16)xn[i];
    *(bf16x8*)(xb + (long)(n0+e)*DD + s*8) = hb;
  }
}

extern "C" void kernel_launch(void* const* d_in, const int* in_sizes, int n_in,
                              void* d_out, int out_size, void* d_ws, size_t ws_size,
                              hipStream_t stream) {
  const int* node_ids   = (const int*)d_in[0];
  const int* edge_index = (const int*)d_in[1];
  const int* edge_ids   = (const int*)d_in[2];
  const float* node_emb = (const float*)d_in[3];
  const float* edge_emb = (const float*)d_in[4];
  const float* ln_w   = (const float*)d_in[5];
  const float* ln_b   = (const float*)d_in[6];
  const float* q_w    = (const float*)d_in[7];
  const float* relA_w = (const float*)d_in[8];
  const float* relA_b = (const float*)d_in[9];
  const float* relB_w = (const float*)d_in[10];
  const float* relB_b = (const float*)d_in[11];
  const float* relG_w = (const float*)d_in[12];
  const float* relG_b = (const float*)d_in[13];
  const float* k_w    = (const float*)d_in[14];
  const float* v_w    = (const float*)d_in[15];
  const float* o_w    = (const float*)d_in[16];
  const float* ff_ln_w= (const float*)d_in[17];
  const float* ff_ln_b= (const float*)d_in[18];
  const float* wi_w   = (const float*)d_in[19];
  const float* wo_w   = (const float*)d_in[20];
  const int* src = edge_index;        // edge_index[0] = j (kv side)
  const int* dst = edge_index + EE;   // edge_index[1] = i (query side)

  float* ws = (float*)d_ws;
  float* x   = ws;  ws += (long)NN*DD;
  float* q   = ws;  ws += (long)NN*DD;
  float* denom = ws; ws += NN*HH;
  float* agg   = ws; ws += (long)NN*DD;
  float* EKf   = ws; ws += (long)LL*RELV*DD;
  int* hist   = (int*)ws; ws += NN;
  int* perm   = (int*)ws; ws += EE;
  ushort* xb  = (ushort*)ws; ws += (long)NN*DD/2;
  ushort* XAb = (ushort*)ws; ws += (long)NN*FFF/2;
  ushort* EAb = (ushort*)ws; ws += (long)LL*RELV*FFF/2;
  ushort* A1b = (ushort*)ws; ws += (long)LL*FFF*DD/2;
  ushort* Gwb = (ushort*)ws; ws += (long)LL*DD*FFF/2;
  ushort* Bwb = (ushort*)ws; ws += (long)LL*DD*FFF/2;
  ushort* Kwb = (ushort*)ws; ws += (long)LL*DD*DD/2;
  ushort* Vwb = (ushort*)ws; ws += (long)LL*DD*DD/2;
  ushort* Qwb = (ushort*)ws; ws += (long)LL*DD*DD/2;
  ushort* Owb = (ushort*)ws; ws += (long)LL*DD*DD/2;
  ushort* Wib = (ushort*)ws; ws += (long)LL*FFF*DD/2;
  ushort* Wob = (ushort*)ws; ws += (long)LL*DD*FFF/2;

  k_gx<<<NN, 128, 0, stream>>>(node_ids, node_emb, x, xb);
  // dst-sort (once; reused by both layers)
  k_zeroh<<<(NN+255)/256, 256, 0, stream>>>(hist);
  k_hist<<<(EE+255)/256, 256, 0, stream>>>(dst, hist);
  k_scan<<<1, 256, 0, stream>>>(hist, hist);   // in-place: hist becomes cursor
  k_scatter<<<(EE+255)/256, 256, 0, stream>>>(dst, hist, perm);
  {
    long nG = (long)LL*DD*FFF, nV = (long)LL*DD*DD, nA1 = (long)FFF*DD;
    for (int l=0; l<LL; ++l){
      k_wprep<<<(DD*FFF/8 + 255)/256, 256, 0, stream>>>(relG_w + (long)l*DD*FFF, Gwb + (long)l*DD*FFF, DD, FFF, FFF, 0);
      k_wprep<<<(DD*FFF/8 + 255)/256, 256, 0, stream>>>(relB_w + (long)l*DD*FFF, Bwb + (long)l*DD*FFF, DD, FFF, FFF, 0);
      k_wprep<<<(DD*DD/8 + 255)/256, 256, 0, stream>>>(k_w + (long)l*DD*256, Kwb + (long)l*DD*DD, DD, DD, 256, 0);
      k_wprep<<<(DD*DD/8 + 255)/256, 256, 0, stream>>>(v_w + (long)l*DD*DD, Vwb + (long)l*DD*DD, DD, DD, DD, 0);
      k_subcast<<<(int)((nA1+255)/256), 256, 0, stream>>>(relA_w + (long)l*FFF*256, A1b + (long)l*FFF*DD, FFF, DD, 256, 0);
      k_ea<<<RELV, 256, 0, stream>>>(edge_emb, relA_w + (long)l*FFF*256, relA_b + (long)l*FFF,
                                     k_w + (long)l*DD*256, EAb + (long)l*RELV*FFF, EKf + (long)l*RELV*DD);
    }
    k_f2b<<<(int)((nV+255)/256), 256, 0, stream>>>(q_w,  Qwb, nV);
    k_f2b<<<(int)((nV+255)/256), 256, 0, stream>>>(o_w,  Owb, nV);
    k_f2b<<<(int)((nG+255)/256), 256, 0, stream>>>(wi_w, Wib, nG);
    k_f2b<<<(int)((nG+255)/256), 256, 0, stream>>>(wo_w, Wob, nG);
  }

  for (int l=0; l<LL; ++l){
    k_lnq_xa<<<NN/NT, 256, 0, stream>>>(x, ln_w + l*DD, ln_b + l*DD,
        Qwb + (long)l*DD*DD, A1b + (long)l*FFF*DD, q, XAb);
    k_init<<<(NN*DD + 255)/256, 256, 0, stream>>>(denom, agg);
    k_edge<<<EE/BM, 512, 0, stream>>>(xb, XAb, EAb + (long)l*RELV*FFF, EKf + (long)l*RELV*DD,
        q, src, dst, edge_ids, perm,
        Gwb + (long)l*DD*FFF,  relG_b + (long)l*DD,
        Bwb + (long)l*DD*FFF,  relB_b + (long)l*DD,
        Kwb + (long)l*DD*DD,   Vwb + (long)l*DD*DD,
        agg, denom);
    k_node<<<NN/NT, 256, 0, stream>>>(agg, denom, Owb + (long)l*DD*DD,
        ff_ln_w + l*DD, ff_ln_b + l*DD,
        Wib + (long)l*FFF*DD, Wob + (long)l*DD*FFF, x, xb);
  }
  hipMemcpyAsync(d_out, x, (size_t)NN*DD*sizeof(float), hipMemcpyDeviceToDevice, stream);
}

// Round 6
// 472.664 us; speedup vs baseline: 1.1856x; 1.1856x over previous
//
#include <hip/hip_runtime.h>
#include <hip/hip_bf16.h>

#define NN 10000
#define EE 160000
#define DD 128
#define HH 4
#define CC 32
#define FFF 512
#define LL 2
#define RELV 100
#define EPS 1e-6f
#define GATE_BIAS 3.0f
#define BM 64
#define NT 16

typedef __bf16 bf16x8 __attribute__((ext_vector_type(8)));
typedef float f32x4 __attribute__((ext_vector_type(4)));
typedef float f32x16 __attribute__((ext_vector_type(16)));

#define MFMA(a,b,c)   __builtin_amdgcn_mfma_f32_16x16x32_bf16((a),(b),(c),0,0,0)
#define MFMA32(a,b,c) __builtin_amdgcn_mfma_f32_32x32x16_bf16((a),(b),(c),0,0,0)

__device__ __forceinline__ int swzK(int e, int b){ return e*256 + (b ^ ((e&7)<<4)); }   // [64][128] bf16
__device__ __forceinline__ int swz128(int e, int b){ return e*256 + (b ^ ((e&7)<<4)); } // [16][128] bf16
__device__ __forceinline__ int swz512(int e, int b){ return e*1024 + (b ^ ((e&7)<<4)); }// [16][512] bf16

__global__ __launch_bounds__(128) void k_gx(
    const int* __restrict__ node_ids, const float* __restrict__ node_emb,
    float* __restrict__ x, ushort* __restrict__ xb){
  int n = blockIdx.x, t = threadIdx.x;
  float v = node_emb[(long)node_ids[n]*DD + t];
  x[(long)n*DD + t] = v;
  __hip_bfloat16 h = __float2bfloat16(v);
  xb[(long)n*DD + t] = *(ushort*)&h;
}

__global__ __launch_bounds__(256) void k_f2b(const float* __restrict__ in, ushort* __restrict__ out, long n){
  long i = (long)blockIdx.x*256 + threadIdx.x;
  if (i < n){
    __hip_bfloat16 h = __float2bfloat16(in[i]);
    out[i] = *(ushort*)&h;
  }
}

__global__ __launch_bounds__(256) void k_subcast(
    const float* __restrict__ in, ushort* __restrict__ out, int OUT, int IN, int instride, int off){
  long tid = (long)blockIdx.x*256 + threadIdx.x;
  if (tid >= (long)OUT*IN) return;
  int o = tid / IN, i = tid % IN;
  __hip_bfloat16 h = __float2bfloat16(in[(long)o*instride + off + i]);
  out[tid] = *(ushort*)&h;
}

// W[OUT][instride] fp32 (cols off..off+IN) -> MFMA32 fragment order bf16
__global__ __launch_bounds__(256) void k_wprep(
    const float* __restrict__ in, ushort* __restrict__ out, int OUT, int IN, int instride, int off){
  int tid = blockIdx.x*256 + threadIdx.x;
  int total = OUT*IN/8;
  if (tid >= total) return;
  int lane = tid & 63;
  int grp  = tid >> 6;
  int nkb  = IN >> 4;
  int kb   = grp % nkb;
  int cb   = grp / nkb;
  int col  = cb*32 + (lane & 31);
  int k0   = kb*16 + (lane >> 5)*8;
  const float* p = in + (long)col*instride + off + k0;
  bf16x8 h;
  #pragma unroll
  for (int j=0;j<8;++j) h[j] = (__bf16)p[j];
  *(bf16x8*)(out + (long)tid*8) = h;
}

// per-relation precompute: EA2[rel][f] = bf16(emb@Aw2^T + Ab), EK[rel][o] = emb@Kw2^T (fp32)
__global__ __launch_bounds__(256) void k_ea(
    const float* __restrict__ edge_emb, const float* __restrict__ relA_w,
    const float* __restrict__ relA_b, const float* __restrict__ k_w,
    ushort* __restrict__ EA2b, float* __restrict__ EKf){
  int rel = blockIdx.x, t = threadIdx.x;
  __shared__ float emb[128];
  if (t < 128) emb[t] = edge_emb[(long)rel*DD + t];
  __syncthreads();
  for (int f=t; f<FFF; f+=256){
    const float* wr = relA_w + (long)f*256 + 128;
    float s = relA_b[f];
    for (int i=0;i<128;++i) s += emb[i]*wr[i];
    __hip_bfloat16 h = __float2bfloat16(s);
    EA2b[(long)rel*FFF + f] = *(ushort*)&h;
  }
  if (t < 128){
    const float* wr = k_w + (long)t*256 + 128;
    float s = 0.f;
    for (int i=0;i<128;++i) s += emb[i]*wr[i];
    EKf[(long)rel*DD + t] = s;
  }
}

__global__ __launch_bounds__(256) void k_init(float* __restrict__ denom, float* __restrict__ agg){
  int i = blockIdx.x*256 + threadIdx.x;
  if (i < NN*DD) agg[i] = 0.f;
  if (i < NN*HH) denom[i] = 0.f;
}

// ---- dst-sort: hist -> scan -> scatter (once per call) ----
__global__ __launch_bounds__(256) void k_zeroh(int* __restrict__ hist){
  int i = blockIdx.x*256 + threadIdx.x;
  if (i < NN) hist[i] = 0;
}
__global__ __launch_bounds__(256) void k_hist(const int* __restrict__ dst, int* __restrict__ hist){
  int e = blockIdx.x*256 + threadIdx.x;
  if (e < EE) atomicAdd(&hist[dst[e]], 1);
}
// exclusive prefix of hist[NN] -> cursor[NN]; single block, 256 threads
__global__ __launch_bounds__(256) void k_scan(const int* __restrict__ hist, int* __restrict__ cursor){
  __shared__ int tsum[256];
  const int t = threadIdx.x;
  const int PER = (NN + 255) / 256;   // 40
  const int base = t*PER;
  int s = 0;
  for (int i=0;i<PER;++i){ int idx = base+i; if (idx < NN) s += hist[idx]; }
  tsum[t] = s;
  __syncthreads();
  if (t == 0){
    int run = 0;
    for (int i=0;i<256;++i){ int v = tsum[i]; tsum[i] = run; run += v; }
  }
  __syncthreads();
  int run = tsum[t];
  for (int i=0;i<PER;++i){
    int idx = base+i;
    if (idx < NN){ int v = hist[idx]; cursor[idx] = run; run += v; }
  }
}
__global__ __launch_bounds__(256) void k_scatter(const int* __restrict__ dst,
    int* __restrict__ cursor, int* __restrict__ perm){
  int e = blockIdx.x*256 + threadIdx.x;
  if (e < EE){
    int p = atomicAdd(&cursor[dst[e]], 1);
    perm[p] = e;
  }
}

// fused LN+q-proj AND XA = x@Aw1^T. 16 nodes/block, 4 waves.
__global__ __launch_bounds__(256) void k_lnq_xa(
    const float* __restrict__ x, const float* __restrict__ lnw, const float* __restrict__ lnb,
    const ushort* __restrict__ qwb, const ushort* __restrict__ a1b,
    float* __restrict__ q, ushort* __restrict__ XAb){
  __shared__ __align__(16) unsigned char HB[NT*256];    // LN'd x (bf16)
  __shared__ __align__(16) unsigned char HR[NT*256];    // raw x (bf16)
  const int n0 = blockIdx.x*NT;
  const int t = threadIdx.x;
  const int e = t>>4, s = t&15;
  const int w = t>>6, l = t&63, lr = l&15, lg = l>>4;
  {
    const float* xp = x + (long)(n0+e)*DD + s*8;
    float xv[8];
    *(float4*)&xv[0] = *(const float4*)xp;
    *(float4*)&xv[4] = *(const float4*)(xp+4);
    float sm = 0.f;
    #pragma unroll
    for (int i=0;i<8;++i) sm += xv[i];
    sm += __shfl_xor(sm,1); sm += __shfl_xor(sm,2);
    sm += __shfl_xor(sm,4); sm += __shfl_xor(sm,8);
    float mu = sm*(1.f/DD);
    float sq = 0.f;
    #pragma unroll
    for (int i=0;i<8;++i){ float d = xv[i]-mu; sq += d*d; }
    sq += __shfl_xor(sq,1); sq += __shfl_xor(sq,2);
    sq += __shfl_xor(sq,4); sq += __shfl_xor(sq,8);
    float rstd = rsqrtf(sq*(1.f/DD) + EPS);
    float4 w0 = *(const float4*)(lnw + s*8), w1 = *(const float4*)(lnw + s*8 + 4);
    float4 b0 = *(const float4*)(lnb + s*8), b1 = *(const float4*)(lnb + s*8 + 4);
    float wv[8] = {w0.x,w0.y,w0.z,w0.w,w1.x,w1.y,w1.z,w1.w};
    float bv[8] = {b0.x,b0.y,b0.z,b0.w,b1.x,b1.y,b1.z,b1.w};
    bf16x8 hb, hr;
    #pragma unroll
    for (int i=0;i<8;++i){
      hb[i] = (__bf16)((xv[i]-mu)*rstd*wv[i] + bv[i]);
      hr[i] = (__bf16)xv[i];
    }
    *(bf16x8*)(HB + swz128(e, s*16)) = hb;
    *(bf16x8*)(HR + swz128(e, s*16)) = hr;
  }
  __syncthreads();
  // q projection (K=128) from HB
  {
    const int o0 = w*32;
    f32x4 z = {0.f,0.f,0.f,0.f};
    f32x4 acc[2] = {z,z};
    #pragma unroll
    for (int k4=0;k4<4;++k4){
      bf16x8 a = *(const bf16x8*)(HB + swz128(lr, k4*64 + lg*16));
      #pragma unroll
      for (int nt=0;nt<2;++nt){
        bf16x8 b = *(const bf16x8*)(qwb + (long)(o0+nt*16+lr)*128 + k4*32 + lg*8);
        acc[nt] = MFMA(a, b, acc[nt]);
      }
    }
    #pragma unroll
    for (int nt=0;nt<2;++nt)
      #pragma unroll
      for (int r=0;r<4;++r)
        q[(long)(n0 + lg*4 + r)*DD + o0 + nt*16 + lr] = acc[nt][r];
  }
  // XA (512 out, K=128) from HR
  {
    const int f0w = w*128;
    f32x4 z = {0.f,0.f,0.f,0.f};
    f32x4 acc[8] = {z,z,z,z,z,z,z,z};
    #pragma unroll
    for (int k4=0;k4<4;++k4){
      bf16x8 a = *(const bf16x8*)(HR + swz128(lr, k4*64 + lg*16));
      #pragma unroll
      for (int nt=0;nt<8;++nt){
        bf16x8 b = *(const bf16x8*)(a1b + (long)(f0w+nt*16+lr)*128 + k4*32 + lg*8);
        acc[nt] = MFMA(a, b, acc[nt]);
      }
    }
    #pragma unroll
    for (int nt=0;nt<8;++nt)
      #pragma unroll
      for (int r=0;r<4;++r){
        __hip_bfloat16 h = __float2bfloat16(acc[nt][r]);
        XAb[(long)(n0+lg*4+r)*FFF + f0w+nt*16+lr] = *(ushort*)&h;
      }
  }
}

// --- fused edge kernel (dst-sorted) ---
// v7: wave (R,C) owns rows 32R..+32 x cols 32C..+32 of BOTH gate and badd GEMMs ->
//     blend entirely in-register (no sigmoid/blend LDS exchange, -2 barriers);
//     INTB double-buffered (1 barrier per celu chunk, -4 barriers);
//     same (R,C) split for K AND V GEMMs -> score reduce spread over all 8 waves
//     (16 serial shuffle-chains/wave instead of 32). Barriers 14 -> 8.
//     Cost: weight fragments read by 2 waves instead of 1 (L2-resident, cheap).
__global__ __launch_bounds__(512,4) void k_edge(
    const ushort* __restrict__ xb, const ushort* __restrict__ XAb,
    const ushort* __restrict__ EAb, const float* __restrict__ EKf,
    const float* __restrict__ q,
    const int* __restrict__ src, const int* __restrict__ dst, const int* __restrict__ eids,
    const int* __restrict__ perm,
    const ushort* __restrict__ Gwb, const float* __restrict__ Gb,
    const ushort* __restrict__ Bwb, const float* __restrict__ Bb,
    const ushort* __restrict__ Kwb, const ushort* __restrict__ Vwb,
    float* __restrict__ agg, float* __restrict__ denom)
{
  __shared__ __align__(16) unsigned char KVB[BM*256];      // 16KB kv2 bf16 [64][128] swz; later AGB rows 0..31 (fp32 linear)
  __shared__ __align__(16) unsigned char INTB[2][BM*256];  // 32KB celu chunk dbuf; INTB[0] later AGB rows 32..63
  __shared__ float EXL[BM][HH];                            // 1KB
  __shared__ int srcl[BM], dstl[BM], eidl[BM];

  const int e0 = blockIdx.x * BM;
  const int t  = threadIdx.x;
  const int w  = t >> 6;
  const int l  = t & 63;
  const int c32 = l & 31;
  const int hi  = l >> 5;
  const int R = w >> 2;          // row-group (edges 32R..32R+32)
  const int C = w & 3;           // col-quarter / head
  const int oc = C*32 + c32;

  if (t < BM){
    int pe = perm[e0+t];
    srcl[t] = src[pe]; dstl[t] = dst[pe]; eidl[t] = eids[pe];
  }
  __syncthreads();

  // stage kv_j = xb[src] into KVB (first read is at blend -- chunk syncs cover the hazard)
  {
    const uint4* xbu = (const uint4*)xb;
    #pragma unroll
    for (int it=0; it<2; ++it){
      int g = it*512 + t;
      int e = g >> 4, qq = g & 15;
      *(uint4*)(KVB + swzK(e, qq*16)) = xbu[(long)srcl[e]*16 + qq];
    }
  }

  f32x16 gbG, gbB;
  {
    float bg = Gb[oc] + GATE_BIAS;
    float bb = Bb[oc];
    #pragma unroll
    for (int i=0;i<16;++i){ gbG[i] = bg; gbB[i] = bb; }
  }

  // prologue: issue chunk-0 gather
  bf16x8 xa8[2], ea8[2];
  #pragma unroll
  for (int it=0; it<2; ++it){
    int g = it*512 + t;
    int e = g >> 4, c8 = g & 15;
    xa8[it] = *(const bf16x8*)(XAb + (long)srcl[e]*FFF + c8*8);
    ea8[it] = *(const bf16x8*)(EAb + (long)eidl[e]*FFF + c8*8);
  }

  // 4 chunks of 128 FF-cols; INTB double-buffered: ONE barrier per chunk.
  // Per chunk: celu -> write INT[p] -> sync -> issue gather(ch+1) -> gate GEMM -> badd GEMM.
  #pragma unroll
  for (int ch=0; ch<4; ++ch){
    bf16x8 o[2];
    #pragma unroll
    for (int it=0; it<2; ++it){
      #pragma unroll
      for (int j=0;j<8;++j){
        float s = (float)xa8[it][j] + (float)ea8[it][j];
        o[it][j] = (__bf16)((s > 0.f) ? s : (__expf(s) - 1.f));
      }
    }
    unsigned char* INTp = INTB[ch & 1];
    #pragma unroll
    for (int it=0; it<2; ++it){
      int g = it*512 + t;
      int e = g >> 4, c8 = g & 15;
      *(bf16x8*)(INTp + swzK(e, c8*16)) = o[it];
    }
    __syncthreads();   // INT[p] visible; GEMM(ch-2) readers of this buffer finished >=1 sync ago
    if (ch < 3){
      #pragma unroll
      for (int it=0; it<2; ++it){
        int g = it*512 + t;
        int e = g >> 4, c8 = g & 15;
        xa8[it] = *(const bf16x8*)(XAb + (long)srcl[e]*FFF + (ch+1)*128 + c8*8);
        ea8[it] = *(const bf16x8*)(EAb + (long)eidl[e]*FFF + (ch+1)*128 + c8*8);
      }
    }
    // gate GEMM: rows 32R.., cols 32C.., K=128
    {
      const ushort* Wg = Gwb + ((long)(C*32 + ch*8)*64 + l)*8;
      bf16x8 wf[8];
      #pragma unroll
      for (int i=0;i<8;++i) wf[i] = *(const bf16x8*)(Wg + (long)i*512);
      #pragma unroll
      for (int i=0;i<8;++i){
        bf16x8 a = *(const bf16x8*)(INTp + swzK(R*32 + c32, i*32 + hi*16));
        gbG = MFMA32(a, wf[i], gbG);
      }
    }
    // badd GEMM: same tile
    {
      const ushort* Wb = Bwb + ((long)(C*32 + ch*8)*64 + l)*8;
      bf16x8 wf[8];
      #pragma unroll
      for (int i=0;i<8;++i) wf[i] = *(const bf16x8*)(Wb + (long)i*512);
      #pragma unroll
      for (int i=0;i<8;++i){
        bf16x8 a = *(const bf16x8*)(INTp + swzK(R*32 + c32, i*32 + hi*16));
        gbB = MFMA32(a, wf[i], gbB);
      }
    }
  }

  // in-register blend: kv2 = badd + sigmoid(gate)*(kv - badd), write back to KVB
  #pragma unroll
  for (int r=0;r<16;++r){
    int row = (r&3) + 8*(r>>2) + 4*hi;
    int gr = R*32 + row;
    float g  = 1.f/(1.f + __expf(-gbG[r]));
    float kv = (float)*(const __bf16*)(KVB + swzK(gr, oc*2));
    float k2 = gbB[r] + g*(kv - gbB[r]);
    *(__bf16*)(KVB + swzK(gr, oc*2)) = (__bf16)k2;
  }
  __syncthreads();   // kv2 ready in KVB

  // K and V GEMMs: wave (R,C) computes K[32R..][32C..] and V[32R..][32C..], K=128
  f32x16 ka, va;
  #pragma unroll
  for (int i=0;i<16;++i){ ka[i] = 0.f; va[i] = 0.f; }
  {
    const ushort* Wk = Kwb + ((long)(C*8)*64 + l)*8;
    bf16x8 wf[8];
    #pragma unroll
    for (int i=0;i<8;++i) wf[i] = *(const bf16x8*)(Wk + (long)i*512);
    #pragma unroll
    for (int i=0;i<8;++i){
      bf16x8 a = *(const bf16x8*)(KVB + swzK(R*32 + c32, i*32 + hi*16));
      ka = MFMA32(a, wf[i], ka);
    }
  }
  {
    const ushort* Wv = Vwb + ((long)(C*8)*64 + l)*8;
    bf16x8 wf[8];
    #pragma unroll
    for (int i=0;i<8;++i) wf[i] = *(const bf16x8*)(Wv + (long)i*512);
    #pragma unroll
    for (int i=0;i<8;++i){
      bf16x8 a = *(const bf16x8*)(KVB + swzK(R*32 + c32, i*32 + hi*16));
      va = MFMA32(a, wf[i], va);
    }
  }
  __syncthreads();   // all KVB reads done; KVB + INTB[0] become fp32 AGB[64][128] (linear)

  // V -> AGB overlay (rows 0..31 -> KVB, 32..63 -> INTB[0])
  #pragma unroll
  for (int r=0;r<16;++r){
    int row = (r&3) + 8*(r>>2) + 4*hi;
    int gr = R*32 + row;
    unsigned char* ab = (gr < 32) ? KVB : INTB[0];
    *(float*)(ab + ((gr & 31)*128 + oc)*4) = va[r];
  }
  // score: k += EK[eid]; dot with q[dst] over head C's 32 cols; EXL = exp
  #pragma unroll
  for (int r=0;r<16;++r){
    int row = (r&3) + 8*(r>>2) + 4*hi;
    int gr = R*32 + row;
    int dn = dstl[gr];
    float kv = ka[r] + EKf[(long)eidl[gr]*DD + oc];
    float p = kv * q[(long)dn*DD + oc];
    p += __shfl_xor(p, 1); p += __shfl_xor(p, 2);
    p += __shfl_xor(p, 4); p += __shfl_xor(p, 8);
    p += __shfl_xor(p, 16);
    if (c32 == 0) EXL[gr][C] = __expf(p);
  }
  __syncthreads();   // EXL + AGB ready

  // segment-reduce (dst-sorted rows): 512 threads = 128 cols x 4 row-groups of 16
  {
    const int col = t & 127;
    const int rg  = t >> 7;
    const int r0  = rg*16;
    const int h   = col >> 5;
    const unsigned char* ab = (rg < 2) ? KVB : INTB[0];   // wave-uniform
    const int rb = (rg & 1) * 16;
    float acc = 0.f;
    int cur = dstl[r0];
    for (int r=0; r<16; ++r){
      int dn = dstl[r0+r];
      if (dn != cur){
        atomicAdd(&agg[(long)cur*DD + col], acc);
        acc = 0.f; cur = dn;
      }
      acc += *(const float*)(ab + ((rb + r)*128 + col)*4) * EXL[r0+r][h];
    }
    atomicAdd(&agg[(long)cur*DD + col], acc);
    if (col < HH){
      float da = 0.f; int cur2 = dstl[r0];
      for (int r=r0; r<r0+16; ++r){
        int dn = dstl[r];
        if (dn != cur2){
          atomicAdd(&denom[cur2*HH + col], da);
          da = 0.f; cur2 = dn;
        }
        da += EXL[r][col];
      }
      atomicAdd(&denom[cur2*HH + col], da);
    }
  }
}

// fused: x1 = x + (agg/denom)@o_w^T;  x = x1 + relu(LN(x1)@wi^T)@wo^T;  emits xb
__global__ __launch_bounds__(256) void k_node(
    const float* __restrict__ agg, const float* __restrict__ denom,
    const ushort* __restrict__ owb,
    const float* __restrict__ lnw, const float* __restrict__ lnb,
    const ushort* __restrict__ wib, const ushort* __restrict__ wob,
    float* __restrict__ x, ushort* __restrict__ xb){
  __shared__ __align__(16) unsigned char AB[NT*256];
  __shared__ __align__(16) unsigned char IB[NT*1024];
  __shared__ __align__(16) float XO[NT][132];
  const int n0 = blockIdx.x*NT;
  const int t = threadIdx.x;
  const int e = t>>4, s = t&15;
  const int w = t>>6, l = t&63, lr = l&15, lg = l>>4;

  {
    const float* ap = agg + (long)(n0+e)*DD + s*8;
    float av[8];
    *(float4*)&av[0] = *(const float4*)ap;
    *(float4*)&av[4] = *(const float4*)(ap+4);
    float dinv = 1.f / denom[(n0+e)*HH + (s>>2)];
    bf16x8 hb;
    #pragma unroll
    for (int i=0;i<8;++i) hb[i] = (__bf16)(av[i]*dinv);
    *(bf16x8*)(AB + swz128(e, s*16)) = hb;
  }
  __syncthreads();

  {
    const int o0 = w*32;
    f32x4 z = {0.f,0.f,0.f,0.f};
    f32x4 acc[2] = {z,z};
    #pragma unroll
    for (int k4=0;k4<4;++k4){
      bf16x8 a = *(const bf16x8*)(AB + swz128(lr, k4*64 + lg*16));
      #pragma unroll
      for (int nt=0;nt<2;++nt){
        bf16x8 b = *(const bf16x8*)(owb + (long)(o0+nt*16+lr)*128 + k4*32 + lg*8);
        acc[nt] = MFMA(a, b, acc[nt]);
      }
    }
    #pragma unroll
    for (int nt=0;nt<2;++nt)
      #pragma unroll
      for (int r=0;r<4;++r)
        XO[lg*4+r][o0+nt*16+lr] = acc[nt][r];
  }
  __syncthreads();

  float x1[8];
  {
    const float* xp = x + (long)(n0+e)*DD + s*8;
    float xv[8];
    *(float4*)&xv[0] = *(const float4*)xp;
    *(float4*)&xv[4] = *(const float4*)(xp+4);
    #pragma unroll
    for (int i=0;i<8;++i) x1[i] = xv[i] + XO[e][s*8+i];
    float sm = 0.f;
    #pragma unroll
    for (int i=0;i<8;++i) sm += x1[i];
    sm += __shfl_xor(sm,1); sm += __shfl_xor(sm,2);
    sm += __shfl_xor(sm,4); sm += __shfl_xor(sm,8);
    float mu = sm*(1.f/DD);
    float sq = 0.f;
    #pragma unroll
    for (int i=0;i<8;++i){ float d = x1[i]-mu; sq += d*d; }
    sq += __shfl_xor(sq,1); sq += __shfl_xor(sq,2);
    sq += __shfl_xor(sq,4); sq += __shfl_xor(sq,8);
    float rstd = rsqrtf(sq*(1.f/DD) + EPS);
    float4 w0 = *(const float4*)(lnw + s*8), w1 = *(const float4*)(lnw + s*8 + 4);
    float4 b0 = *(const float4*)(lnb + s*8), b1 = *(const float4*)(lnb + s*8 + 4);
    float wv[8] = {w0.x,w0.y,w0.z,w0.w,w1.x,w1.y,w1.z,w1.w};
    float bv[8] = {b0.x,b0.y,b0.z,b0.w,b1.x,b1.y,b1.z,b1.w};
    bf16x8 hb;
    #pragma unroll
    for (int i=0;i<8;++i) hb[i] = (__bf16)((x1[i]-mu)*rstd*wv[i] + bv[i]);
    __syncthreads();
    *(bf16x8*)(AB + swz128(e, s*16)) = hb;
  }
  __syncthreads();

  {
    const int f0w = w*128;
    f32x4 z = {0.f,0.f,0.f,0.f};
    f32x4 acc[8] = {z,z,z,z,z,z,z,z};
    #pragma unroll
    for (int k4=0;k4<4;++k4){
      bf16x8 a = *(const bf16x8*)(AB + swz128(lr, k4*64 + lg*16));
      #pragma unroll
      for (int nt=0;nt<8;++nt){
        bf16x8 b = *(const bf16x8*)(wib + (long)(f0w+nt*16+lr)*128 + k4*32 + lg*8);
        acc[nt] = MFMA(a, b, acc[nt]);
      }
    }
    #pragma unroll
    for (int nt=0;nt<8;++nt)
      #pragma unroll
      for (int r=0;r<4;++r){
        int e2 = lg*4 + r;
        int f = f0w + nt*16 + lr;
        float va = acc[nt][r];
        *(__bf16*)(IB + swz512(e2, f*2)) = (__bf16)fmaxf(va, 0.f);
      }
  }
  __syncthreads();

  {
    const int o0 = w*32;
    f32x4 z = {0.f,0.f,0.f,0.f};
    f32x4 acc[2] = {z,z};
    #pragma unroll
    for (int k16=0;k16<16;++k16){
      bf16x8 a = *(const bf16x8*)(IB + swz512(lr, k16*64 + lg*16));
      #pragma unroll
      for (int nt=0;nt<2;++nt){
        bf16x8 b = *(const bf16x8*)(wob + (long)(o0+nt*16+lr)*512 + k16*32 + lg*8);
        acc[nt] = MFMA(a, b, acc[nt]);
      }
    }
    #pragma unroll
    for (int nt=0;nt<2;++nt)
      #pragma unroll
      for (int r=0;r<4;++r)
        XO[lg*4+r][o0+nt*16+lr] = acc[nt][r];
  }
  __syncthreads();

  {
    float xn[8];
    #pragma unroll
    for (int i=0;i<8;++i) xn[i] = x1[i] + XO[e][s*8+i];
    float* xp = x + (long)(n0+e)*DD + s*8;
    *(float4*)xp = *(float4*)&xn[0];
    *(float4*)(xp+4) = *(float4*)&xn[4];
    bf16x8 hb;
    #pragma unroll
    for (int i=0;i<8;++i) hb[i] = (__bf16)xn[i];
    *(bf16x8*)(xb + (long)(n0+e)*DD + s*8) = hb;
  }
}

extern "C" void kernel_launch(void* const* d_in, const int* in_sizes, int n_in,
                              void* d_out, int out_size, void* d_ws, size_t ws_size,
                              hipStream_t stream) {
  const int* node_ids   = (const int*)d_in[0];
  const int* edge_index = (const int*)d_in[1];
  const int* edge_ids   = (const int*)d_in[2];
  const float* node_emb = (const float*)d_in[3];
  const float* edge_emb = (const float*)d_in[4];
  const float* ln_w   = (const float*)d_in[5];
  const float* ln_b   = (const float*)d_in[6];
  const float* q_w    = (const float*)d_in[7];
  const float* relA_w = (const float*)d_in[8];
  const float* relA_b = (const float*)d_in[9];
  const float* relB_w = (const float*)d_in[10];
  const float* relB_b = (const float*)d_in[11];
  const float* relG_w = (const float*)d_in[12];
  const float* relG_b = (const float*)d_in[13];
  const float* k_w    = (const float*)d_in[14];
  const float* v_w    = (const float*)d_in[15];
  const float* o_w    = (const float*)d_in[16];
  const float* ff_ln_w= (const float*)d_in[17];
  const float* ff_ln_b= (const float*)d_in[18];
  const float* wi_w   = (const float*)d_in[19];
  const float* wo_w   = (const float*)d_in[20];
  const int* src = edge_index;        // edge_index[0] = j (kv side)
  const int* dst = edge_index + EE;   // edge_index[1] = i (query side)

  float* ws = (float*)d_ws;
  float* x   = ws;  ws += (long)NN*DD;
  float* q   = ws;  ws += (long)NN*DD;
  float* denom = ws; ws += NN*HH;
  float* agg   = ws; ws += (long)NN*DD;
  float* EKf   = ws; ws += (long)LL*RELV*DD;
  int* hist   = (int*)ws; ws += NN;
  int* perm   = (int*)ws; ws += EE;
  ushort* xb  = (ushort*)ws; ws += (long)NN*DD/2;
  ushort* XAb = (ushort*)ws; ws += (long)NN*FFF/2;
  ushort* EAb = (ushort*)ws; ws += (long)LL*RELV*FFF/2;
  ushort* A1b = (ushort*)ws; ws += (long)LL*FFF*DD/2;
  ushort* Gwb = (ushort*)ws; ws += (long)LL*DD*FFF/2;
  ushort* Bwb = (ushort*)ws; ws += (long)LL*DD*FFF/2;
  ushort* Kwb = (ushort*)ws; ws += (long)LL*DD*DD/2;
  ushort* Vwb = (ushort*)ws; ws += (long)LL*DD*DD/2;
  ushort* Qwb = (ushort*)ws; ws += (long)LL*DD*DD/2;
  ushort* Owb = (ushort*)ws; ws += (long)LL*DD*DD/2;
  ushort* Wib = (ushort*)ws; ws += (long)LL*FFF*DD/2;
  ushort* Wob = (ushort*)ws; ws += (long)LL*DD*FFF/2;

  k_gx<<<NN, 128, 0, stream>>>(node_ids, node_emb, x, xb);
  // dst-sort (once; reused by both layers)
  k_zeroh<<<(NN+255)/256, 256, 0, stream>>>(hist);
  k_hist<<<(EE+255)/256, 256, 0, stream>>>(dst, hist);
  k_scan<<<1, 256, 0, stream>>>(hist, hist);   // in-place: hist becomes cursor
  k_scatter<<<(EE+255)/256, 256, 0, stream>>>(dst, hist, perm);
  {
    long nG = (long)LL*DD*FFF, nV = (long)LL*DD*DD, nA1 = (long)FFF*DD;
    for (int l=0; l<LL; ++l){
      k_wprep<<<(DD*FFF/8 + 255)/256, 256, 0, stream>>>(relG_w + (long)l*DD*FFF, Gwb + (long)l*DD*FFF, DD, FFF, FFF, 0);
      k_wprep<<<(DD*FFF/8 + 255)/256, 256, 0, stream>>>(relB_w + (long)l*DD*FFF, Bwb + (long)l*DD*FFF, DD, FFF, FFF, 0);
      k_wprep<<<(DD*DD/8 + 255)/256, 256, 0, stream>>>(k_w + (long)l*DD*256, Kwb + (long)l*DD*DD, DD, DD, 256, 0);
      k_wprep<<<(DD*DD/8 + 255)/256, 256, 0, stream>>>(v_w + (long)l*DD*DD, Vwb + (long)l*DD*DD, DD, DD, DD, 0);
      k_subcast<<<(int)((nA1+255)/256), 256, 0, stream>>>(relA_w + (long)l*FFF*256, A1b + (long)l*FFF*DD, FFF, DD, 256, 0);
      k_ea<<<RELV, 256, 0, stream>>>(edge_emb, relA_w + (long)l*FFF*256, relA_b + (long)l*FFF,
                                     k_w + (long)l*DD*256, EAb + (long)l*RELV*FFF, EKf + (long)l*RELV*DD);
    }
    k_f2b<<<(int)((nV+255)/256), 256, 0, stream>>>(q_w,  Qwb, nV);
    k_f2b<<<(int)((nV+255)/256), 256, 0, stream>>>(o_w,  Owb, nV);
    k_f2b<<<(int)((nG+255)/256), 256, 0, stream>>>(wi_w, Wib, nG);
    k_f2b<<<(int)((nG+255)/256), 256, 0, stream>>>(wo_w, Wob, nG);
  }

  for (int l=0; l<LL; ++l){
    k_lnq_xa<<<NN/NT, 256, 0, stream>>>(x, ln_w + l*DD, ln_b + l*DD,
        Qwb + (long)l*DD*DD, A1b + (long)l*FFF*DD, q, XAb);
    k_init<<<(NN*DD + 255)/256, 256, 0, stream>>>(denom, agg);
    k_edge<<<EE/BM, 512, 0, stream>>>(xb, XAb, EAb + (long)l*RELV*FFF, EKf + (long)l*RELV*DD,
        q, src, dst, edge_ids, perm,
        Gwb + (long)l*DD*FFF,  relG_b + (long)l*DD,
        Bwb + (long)l*DD*FFF,  relB_b + (long)l*DD,
        Kwb + (long)l*DD*DD,   Vwb + (long)l*DD*DD,
        agg, denom);
    k_node<<<NN/NT, 256, 0, stream>>>(agg, denom, Owb + (long)l*DD*DD,
        ff_ln_w + l*DD, ff_ln_b + l*DD,
        Wib + (long)l*FFF*DD, Wob + (long)l*DD*FFF, x, xb);
  }
  hipMemcpyAsync(d_out, x, (size_t)NN*DD*sizeof(float), hipMemcpyDeviceToDevice, stream);
}

// Round 7
// 443.233 us; speedup vs baseline: 1.2643x; 1.0664x over previous
//
#include <hip/hip_runtime.h>
#include <hip/hip_bf16.h>

#define NN 10000
#define EE 160000
#define DD 128
#define HH 4
#define CC 32
#define FFF 512
#define LL 2
#define RELV 100
#define EPS 1e-6f
#define GATE_BIAS 3.0f
#define BM 64
#define NT 16

typedef __bf16 bf16x8 __attribute__((ext_vector_type(8)));
typedef float f32x4 __attribute__((ext_vector_type(4)));
typedef float f32x16 __attribute__((ext_vector_type(16)));

#define MFMA(a,b,c)   __builtin_amdgcn_mfma_f32_16x16x32_bf16((a),(b),(c),0,0,0)
#define MFMA32(a,b,c) __builtin_amdgcn_mfma_f32_32x32x16_bf16((a),(b),(c),0,0,0)

__device__ __forceinline__ int swzK(int e, int b){ return e*256 + (b ^ ((e&7)<<4)); }   // [64][128] bf16
__device__ __forceinline__ int swz128(int e, int b){ return e*256 + (b ^ ((e&7)<<4)); } // [16][128] bf16
__device__ __forceinline__ int swz512(int e, int b){ return e*1024 + (b ^ ((e&7)<<4)); }// [16][512] bf16

// v8: hist zeroing folded in (saves k_zeroh launch)
__global__ __launch_bounds__(128) void k_gx(
    const int* __restrict__ node_ids, const float* __restrict__ node_emb,
    float* __restrict__ x, ushort* __restrict__ xb, int* __restrict__ hist){
  int n = blockIdx.x, t = threadIdx.x;
  if (t == 0) hist[n] = 0;
  float v = node_emb[(long)node_ids[n]*DD + t];
  x[(long)n*DD + t] = v;
  __hip_bfloat16 h = __float2bfloat16(v);
  xb[(long)n*DD + t] = *(ushort*)&h;
}

// W[?][instride] fp32 -> MFMA32 fragment order bf16 (device helper)
__device__ __forceinline__ void wprep_one(
    const float* __restrict__ in, ushort* __restrict__ out, int tid, int IN, int instride){
  int lane = tid & 63;
  int grp  = tid >> 6;
  int nkb  = IN >> 4;
  int kb   = grp % nkb;
  int cb   = grp / nkb;
  int col  = cb*32 + (lane & 31);
  int k0   = kb*16 + (lane >> 5)*8;
  const float* p = in + (long)col*instride + k0;
  bf16x8 h;
  #pragma unroll
  for (int j=0;j<8;++j) h[j] = (__bf16)p[j];
  *(bf16x8*)(out + (long)tid*8) = h;
}

// v8: fused per-layer weight prep (Gwb,Bwb,Kwb,Vwb wprep + A1b subcast), one launch/layer.
// grid 256 x 256 = 65536 threads = FFF*DD.
__global__ __launch_bounds__(256) void k_prep(
    const float* __restrict__ relG_w, const float* __restrict__ relB_w,
    const float* __restrict__ k_w, const float* __restrict__ v_w,
    const float* __restrict__ relA_w,
    ushort* __restrict__ Gwb, ushort* __restrict__ Bwb,
    ushort* __restrict__ Kwb, ushort* __restrict__ Vwb, ushort* __restrict__ A1b){
  int tid = blockIdx.x*256 + threadIdx.x;
  if (tid < DD*FFF/8){
    wprep_one(relG_w, Gwb, tid, FFF, FFF);
    wprep_one(relB_w, Bwb, tid, FFF, FFF);
  }
  if (tid < DD*DD/8){
    wprep_one(k_w, Kwb, tid, DD, 256);
    wprep_one(v_w, Vwb, tid, DD, DD);
  }
  {
    int o = tid / DD, i = tid % DD;   // tid < FFF*DD always (grid sized exactly)
    __hip_bfloat16 h = __float2bfloat16(relA_w[(long)o*256 + i]);
    A1b[tid] = *(ushort*)&h;
  }
}

// v8: the 4 plain casts (Qw,Ow,Wi,Wo both layers) in one launch. grid 512 x 256 = 131072 = nG.
__global__ __launch_bounds__(256) void k_f2b4(
    const float* __restrict__ q_w, const float* __restrict__ o_w,
    const float* __restrict__ wi_w, const float* __restrict__ wo_w,
    ushort* __restrict__ Qwb, ushort* __restrict__ Owb,
    ushort* __restrict__ Wib, ushort* __restrict__ Wob){
  long i = (long)blockIdx.x*256 + threadIdx.x;
  const long nV = (long)LL*DD*DD;    // 32768
  if (i < nV){
    __hip_bfloat16 h1 = __float2bfloat16(q_w[i]); Qwb[i] = *(ushort*)&h1;
    __hip_bfloat16 h2 = __float2bfloat16(o_w[i]); Owb[i] = *(ushort*)&h2;
  }
  {
    __hip_bfloat16 h3 = __float2bfloat16(wi_w[i]); Wib[i] = *(ushort*)&h3;
    __hip_bfloat16 h4 = __float2bfloat16(wo_w[i]); Wob[i] = *(ushort*)&h4;
  }
}

// per-relation precompute: EA2[rel][f] = bf16(emb@Aw2^T + Ab), EK[rel][o] = emb@Kw2^T (fp32)
__global__ __launch_bounds__(256) void k_ea(
    const float* __restrict__ edge_emb, const float* __restrict__ relA_w,
    const float* __restrict__ relA_b, const float* __restrict__ k_w,
    ushort* __restrict__ EA2b, float* __restrict__ EKf){
  int rel = blockIdx.x, t = threadIdx.x;
  __shared__ float emb[128];
  if (t < 128) emb[t] = edge_emb[(long)rel*DD + t];
  __syncthreads();
  for (int f=t; f<FFF; f+=256){
    const float* wr = relA_w + (long)f*256 + 128;
    float s = relA_b[f];
    for (int i=0;i<128;++i) s += emb[i]*wr[i];
    __hip_bfloat16 h = __float2bfloat16(s);
    EA2b[(long)rel*FFF + f] = *(ushort*)&h;
  }
  if (t < 128){
    const float* wr = k_w + (long)t*256 + 128;
    float s = 0.f;
    for (int i=0;i<128;++i) s += emb[i]*wr[i];
    EKf[(long)rel*DD + t] = s;
  }
}

// ---- dst-sort: hist -> scan -> scatter (once per call) ----
__global__ __launch_bounds__(256) void k_hist(const int* __restrict__ dst, int* __restrict__ hist){
  int e = blockIdx.x*256 + threadIdx.x;
  if (e < EE) atomicAdd(&hist[dst[e]], 1);
}
// exclusive prefix of hist[NN] -> cursor[NN]; single block, 256 threads
__global__ __launch_bounds__(256) void k_scan(const int* __restrict__ hist, int* __restrict__ cursor){
  __shared__ int tsum[256];
  const int t = threadIdx.x;
  const int PER = (NN + 255) / 256;   // 40
  const int base = t*PER;
  int s = 0;
  for (int i=0;i<PER;++i){ int idx = base+i; if (idx < NN) s += hist[idx]; }
  tsum[t] = s;
  __syncthreads();
  if (t == 0){
    int run = 0;
    for (int i=0;i<256;++i){ int v = tsum[i]; tsum[i] = run; run += v; }
  }
  __syncthreads();
  int run = tsum[t];
  for (int i=0;i<PER;++i){
    int idx = base+i;
    if (idx < NN){ int v = hist[idx]; cursor[idx] = run; run += v; }
  }
}
__global__ __launch_bounds__(256) void k_scatter(const int* __restrict__ dst,
    int* __restrict__ cursor, int* __restrict__ perm){
  int e = blockIdx.x*256 + threadIdx.x;
  if (e < EE){
    int p = atomicAdd(&cursor[dst[e]], 1);
    perm[p] = e;
  }
}

// fused LN+q-proj AND XA = x@Aw1^T. 16 nodes/block, 4 waves.
// v8: also zeroes agg/denom for its 16 nodes (replaces the 5000-block k_init launch).
__global__ __launch_bounds__(256) void k_lnq_xa(
    const float* __restrict__ x, const float* __restrict__ lnw, const float* __restrict__ lnb,
    const ushort* __restrict__ qwb, const ushort* __restrict__ a1b,
    float* __restrict__ q, ushort* __restrict__ XAb,
    float* __restrict__ agg, float* __restrict__ denom){
  __shared__ __align__(16) unsigned char HB[NT*256];    // LN'd x (bf16)
  __shared__ __align__(16) unsigned char HR[NT*256];    // raw x (bf16)
  const int n0 = blockIdx.x*NT;
  const int t = threadIdx.x;
  const int e = t>>4, s = t&15;
  const int w = t>>6, l = t&63, lr = l&15, lg = l>>4;
  // zero agg rows n0..n0+16 (2048 floats = 256 thr x 8) and denom (64)
  {
    float4 z4 = {0.f,0.f,0.f,0.f};
    float* ap = agg + (long)n0*DD + t*8;
    *(float4*)ap = z4; *(float4*)(ap+4) = z4;
    if (t < NT*HH) denom[n0*HH + t] = 0.f;
  }
  {
    const float* xp = x + (long)(n0+e)*DD + s*8;
    float xv[8];
    *(float4*)&xv[0] = *(const float4*)xp;
    *(float4*)&xv[4] = *(const float4*)(xp+4);
    float sm = 0.f;
    #pragma unroll
    for (int i=0;i<8;++i) sm += xv[i];
    sm += __shfl_xor(sm,1); sm += __shfl_xor(sm,2);
    sm += __shfl_xor(sm,4); sm += __shfl_xor(sm,8);
    float mu = sm*(1.f/DD);
    float sq = 0.f;
    #pragma unroll
    for (int i=0;i<8;++i){ float d = xv[i]-mu; sq += d*d; }
    sq += __shfl_xor(sq,1); sq += __shfl_xor(sq,2);
    sq += __shfl_xor(sq,4); sq += __shfl_xor(sq,8);
    float rstd = rsqrtf(sq*(1.f/DD) + EPS);
    float4 w0 = *(const float4*)(lnw + s*8), w1 = *(const float4*)(lnw + s*8 + 4);
    float4 b0 = *(const float4*)(lnb + s*8), b1 = *(const float4*)(lnb + s*8 + 4);
    float wv[8] = {w0.x,w0.y,w0.z,w0.w,w1.x,w1.y,w1.z,w1.w};
    float bv[8] = {b0.x,b0.y,b0.z,b0.w,b1.x,b1.y,b1.z,b1.w};
    bf16x8 hb, hr;
    #pragma unroll
    for (int i=0;i<8;++i){
      hb[i] = (__bf16)((xv[i]-mu)*rstd*wv[i] + bv[i]);
      hr[i] = (__bf16)xv[i];
    }
    *(bf16x8*)(HB + swz128(e, s*16)) = hb;
    *(bf16x8*)(HR + swz128(e, s*16)) = hr;
  }
  __syncthreads();
  // q projection (K=128) from HB
  {
    const int o0 = w*32;
    f32x4 z = {0.f,0.f,0.f,0.f};
    f32x4 acc[2] = {z,z};
    #pragma unroll
    for (int k4=0;k4<4;++k4){
      bf16x8 a = *(const bf16x8*)(HB + swz128(lr, k4*64 + lg*16));
      #pragma unroll
      for (int nt=0;nt<2;++nt){
        bf16x8 b = *(const bf16x8*)(qwb + (long)(o0+nt*16+lr)*128 + k4*32 + lg*8);
        acc[nt] = MFMA(a, b, acc[nt]);
      }
    }
    #pragma unroll
    for (int nt=0;nt<2;++nt)
      #pragma unroll
      for (int r=0;r<4;++r)
        q[(long)(n0 + lg*4 + r)*DD + o0 + nt*16 + lr] = acc[nt][r];
  }
  // XA (512 out, K=128) from HR
  {
    const int f0w = w*128;
    f32x4 z = {0.f,0.f,0.f,0.f};
    f32x4 acc[8] = {z,z,z,z,z,z,z,z};
    #pragma unroll
    for (int k4=0;k4<4;++k4){
      bf16x8 a = *(const bf16x8*)(HR + swz128(lr, k4*64 + lg*16));
      #pragma unroll
      for (int nt=0;nt<8;++nt){
        bf16x8 b = *(const bf16x8*)(a1b + (long)(f0w+nt*16+lr)*128 + k4*32 + lg*8);
        acc[nt] = MFMA(a, b, acc[nt]);
      }
    }
    #pragma unroll
    for (int nt=0;nt<8;++nt)
      #pragma unroll
      for (int r=0;r<4;++r){
        __hip_bfloat16 h = __float2bfloat16(acc[nt][r]);
        XAb[(long)(n0+lg*4+r)*FFF + f0w+nt*16+lr] = *(ushort*)&h;
      }
  }
}

// --- fused edge kernel (dst-sorted) ---
// v7: in-register blend, dbuf INTB, (R,C) wave tiling, 8 barriers. (513 -> 472)
// v8: A-fragments hoisted to registers and reused across the gate/badd GEMM pair and
//     the K/V GEMM pair -> halves ds_read_b128 in the MFMA phases.
__global__ __launch_bounds__(512,4) void k_edge(
    const ushort* __restrict__ xb, const ushort* __restrict__ XAb,
    const ushort* __restrict__ EAb, const float* __restrict__ EKf,
    const float* __restrict__ q,
    const int* __restrict__ src, const int* __restrict__ dst, const int* __restrict__ eids,
    const int* __restrict__ perm,
    const ushort* __restrict__ Gwb, const float* __restrict__ Gb,
    const ushort* __restrict__ Bwb, const float* __restrict__ Bb,
    const ushort* __restrict__ Kwb, const ushort* __restrict__ Vwb,
    float* __restrict__ agg, float* __restrict__ denom)
{
  __shared__ __align__(16) unsigned char KVB[BM*256];      // 16KB kv2 bf16 [64][128] swz; later AGB rows 0..31 (fp32 linear)
  __shared__ __align__(16) unsigned char INTB[2][BM*256];  // 32KB celu chunk dbuf; INTB[0] later AGB rows 32..63
  __shared__ float EXL[BM][HH];                            // 1KB
  __shared__ int srcl[BM], dstl[BM], eidl[BM];

  const int e0 = blockIdx.x * BM;
  const int t  = threadIdx.x;
  const int w  = t >> 6;
  const int l  = t & 63;
  const int c32 = l & 31;
  const int hi  = l >> 5;
  const int R = w >> 2;          // row-group (edges 32R..32R+32)
  const int C = w & 3;           // col-quarter / head
  const int oc = C*32 + c32;

  if (t < BM){
    int pe = perm[e0+t];
    srcl[t] = src[pe]; dstl[t] = dst[pe]; eidl[t] = eids[pe];
  }
  __syncthreads();

  // stage kv_j = xb[src] into KVB (first read is at blend -- chunk syncs cover the hazard)
  {
    const uint4* xbu = (const uint4*)xb;
    #pragma unroll
    for (int it=0; it<2; ++it){
      int g = it*512 + t;
      int e = g >> 4, qq = g & 15;
      *(uint4*)(KVB + swzK(e, qq*16)) = xbu[(long)srcl[e]*16 + qq];
    }
  }

  f32x16 gbG, gbB;
  {
    float bg = Gb[oc] + GATE_BIAS;
    float bb = Bb[oc];
    #pragma unroll
    for (int i=0;i<16;++i){ gbG[i] = bg; gbB[i] = bb; }
  }

  // prologue: issue chunk-0 gather
  bf16x8 xa8[2], ea8[2];
  #pragma unroll
  for (int it=0; it<2; ++it){
    int g = it*512 + t;
    int e = g >> 4, c8 = g & 15;
    xa8[it] = *(const bf16x8*)(XAb + (long)srcl[e]*FFF + c8*8);
    ea8[it] = *(const bf16x8*)(EAb + (long)eidl[e]*FFF + c8*8);
  }

  // 4 chunks of 128 FF-cols; INTB double-buffered: ONE barrier per chunk.
  #pragma unroll
  for (int ch=0; ch<4; ++ch){
    bf16x8 o[2];
    #pragma unroll
    for (int it=0; it<2; ++it){
      #pragma unroll
      for (int j=0;j<8;++j){
        float s = (float)xa8[it][j] + (float)ea8[it][j];
        o[it][j] = (__bf16)((s > 0.f) ? s : (__expf(s) - 1.f));
      }
    }
    unsigned char* INTp = INTB[ch & 1];
    #pragma unroll
    for (int it=0; it<2; ++it){
      int g = it*512 + t;
      int e = g >> 4, c8 = g & 15;
      *(bf16x8*)(INTp + swzK(e, c8*16)) = o[it];
    }
    __syncthreads();   // INT[p] visible; GEMM(ch-2) readers of this buffer finished >=1 sync ago
    if (ch < 3){
      #pragma unroll
      for (int it=0; it<2; ++it){
        int g = it*512 + t;
        int e = g >> 4, c8 = g & 15;
        xa8[it] = *(const bf16x8*)(XAb + (long)srcl[e]*FFF + (ch+1)*128 + c8*8);
        ea8[it] = *(const bf16x8*)(EAb + (long)eidl[e]*FFF + (ch+1)*128 + c8*8);
      }
    }
    // A-fragments once, reused by gate AND badd GEMMs
    bf16x8 af[8];
    #pragma unroll
    for (int i=0;i<8;++i) af[i] = *(const bf16x8*)(INTp + swzK(R*32 + c32, i*32 + hi*16));
    {
      const ushort* Wg = Gwb + ((long)(C*32 + ch*8)*64 + l)*8;
      bf16x8 wf[8];
      #pragma unroll
      for (int i=0;i<8;++i) wf[i] = *(const bf16x8*)(Wg + (long)i*512);
      #pragma unroll
      for (int i=0;i<8;++i) gbG = MFMA32(af[i], wf[i], gbG);
    }
    {
      const ushort* Wb = Bwb + ((long)(C*32 + ch*8)*64 + l)*8;
      bf16x8 wf[8];
      #pragma unroll
      for (int i=0;i<8;++i) wf[i] = *(const bf16x8*)(Wb + (long)i*512);
      #pragma unroll
      for (int i=0;i<8;++i) gbB = MFMA32(af[i], wf[i], gbB);
    }
  }

  // in-register blend: kv2 = badd + sigmoid(gate)*(kv - badd), write back to KVB
  #pragma unroll
  for (int r=0;r<16;++r){
    int row = (r&3) + 8*(r>>2) + 4*hi;
    int gr = R*32 + row;
    float g  = 1.f/(1.f + __expf(-gbG[r]));
    float kv = (float)*(const __bf16*)(KVB + swzK(gr, oc*2));
    float k2 = gbB[r] + g*(kv - gbB[r]);
    *(__bf16*)(KVB + swzK(gr, oc*2)) = (__bf16)k2;
  }
  __syncthreads();   // kv2 ready in KVB

  // K and V GEMMs: wave (R,C) computes K[32R..][32C..] and V[32R..][32C..], K=128
  f32x16 ka, va;
  #pragma unroll
  for (int i=0;i<16;++i){ ka[i] = 0.f; va[i] = 0.f; }
  {
    bf16x8 af[8];
    #pragma unroll
    for (int i=0;i<8;++i) af[i] = *(const bf16x8*)(KVB + swzK(R*32 + c32, i*32 + hi*16));
    {
      const ushort* Wk = Kwb + ((long)(C*8)*64 + l)*8;
      bf16x8 wf[8];
      #pragma unroll
      for (int i=0;i<8;++i) wf[i] = *(const bf16x8*)(Wk + (long)i*512);
      #pragma unroll
      for (int i=0;i<8;++i) ka = MFMA32(af[i], wf[i], ka);
    }
    {
      const ushort* Wv = Vwb + ((long)(C*8)*64 + l)*8;
      bf16x8 wf[8];
      #pragma unroll
      for (int i=0;i<8;++i) wf[i] = *(const bf16x8*)(Wv + (long)i*512);
      #pragma unroll
      for (int i=0;i<8;++i) va = MFMA32(af[i], wf[i], va);
    }
  }
  __syncthreads();   // all KVB reads done; KVB + INTB[0] become fp32 AGB[64][128] (linear)

  // V -> AGB overlay (rows 0..31 -> KVB, 32..63 -> INTB[0])
  #pragma unroll
  for (int r=0;r<16;++r){
    int row = (r&3) + 8*(r>>2) + 4*hi;
    int gr = R*32 + row;
    unsigned char* ab = (gr < 32) ? KVB : INTB[0];
    *(float*)(ab + ((gr & 31)*128 + oc)*4) = va[r];
  }
  // score: k += EK[eid]; dot with q[dst] over head C's 32 cols; EXL = exp
  #pragma unroll
  for (int r=0;r<16;++r){
    int row = (r&3) + 8*(r>>2) + 4*hi;
    int gr = R*32 + row;
    int dn = dstl[gr];
    float kv = ka[r] + EKf[(long)eidl[gr]*DD + oc];
    float p = kv * q[(long)dn*DD + oc];
    p += __shfl_xor(p, 1); p += __shfl_xor(p, 2);
    p += __shfl_xor(p, 4); p += __shfl_xor(p, 8);
    p += __shfl_xor(p, 16);
    if (c32 == 0) EXL[gr][C] = __expf(p);
  }
  __syncthreads();   // EXL + AGB ready

  // segment-reduce (dst-sorted rows): 512 threads = 128 cols x 4 row-groups of 16
  {
    const int col = t & 127;
    const int rg  = t >> 7;
    const int r0  = rg*16;
    const int h   = col >> 5;
    const unsigned char* ab = (rg < 2) ? KVB : INTB[0];   // wave-uniform
    const int rb = (rg & 1) * 16;
    float acc = 0.f;
    int cur = dstl[r0];
    for (int r=0; r<16; ++r){
      int dn = dstl[r0+r];
      if (dn != cur){
        atomicAdd(&agg[(long)cur*DD + col], acc);
        acc = 0.f; cur = dn;
      }
      acc += *(const float*)(ab + ((rb + r)*128 + col)*4) * EXL[r0+r][h];
    }
    atomicAdd(&agg[(long)cur*DD + col], acc);
    if (col < HH){
      float da = 0.f; int cur2 = dstl[r0];
      for (int r=r0; r<r0+16; ++r){
        int dn = dstl[r];
        if (dn != cur2){
          atomicAdd(&denom[cur2*HH + col], da);
          da = 0.f; cur2 = dn;
        }
        da += EXL[r][col];
      }
      atomicAdd(&denom[cur2*HH + col], da);
    }
  }
}

// fused: x1 = x + (agg/denom)@o_w^T;  x = x1 + relu(LN(x1)@wi^T)@wo^T;  emits xb
__global__ __launch_bounds__(256) void k_node(
    const float* __restrict__ agg, const float* __restrict__ denom,
    const ushort* __restrict__ owb,
    const float* __restrict__ lnw, const float* __restrict__ lnb,
    const ushort* __restrict__ wib, const ushort* __restrict__ wob,
    float* __restrict__ x, ushort* __restrict__ xb){
  __shared__ __align__(16) unsigned char AB[NT*256];
  __shared__ __align__(16) unsigned char IB[NT*1024];
  __shared__ __align__(16) float XO[NT][132];
  const int n0 = blockIdx.x*NT;
  const int t = threadIdx.x;
  const int e = t>>4, s = t&15;
  const int w = t>>6, l = t&63, lr = l&15, lg = l>>4;

  {
    const float* ap = agg + (long)(n0+e)*DD + s*8;
    float av[8];
    *(float4*)&av[0] = *(const float4*)ap;
    *(float4*)&av[4] = *(const float4*)(ap+4);
    float dinv = 1.f / denom[(n0+e)*HH + (s>>2)];
    bf16x8 hb;
    #pragma unroll
    for (int i=0;i<8;++i) hb[i] = (__bf16)(av[i]*dinv);
    *(bf16x8*)(AB + swz128(e, s*16)) = hb;
  }
  __syncthreads();

  {
    const int o0 = w*32;
    f32x4 z = {0.f,0.f,0.f,0.f};
    f32x4 acc[2] = {z,z};
    #pragma unroll
    for (int k4=0;k4<4;++k4){
      bf16x8 a = *(const bf16x8*)(AB + swz128(lr, k4*64 + lg*16));
      #pragma unroll
      for (int nt=0;nt<2;++nt){
        bf16x8 b = *(const bf16x8*)(owb + (long)(o0+nt*16+lr)*128 + k4*32 + lg*8);
        acc[nt] = MFMA(a, b, acc[nt]);
      }
    }
    #pragma unroll
    for (int nt=0;nt<2;++nt)
      #pragma unroll
      for (int r=0;r<4;++r)
        XO[lg*4+r][o0+nt*16+lr] = acc[nt][r];
  }
  __syncthreads();

  float x1[8];
  {
    const float* xp = x + (long)(n0+e)*DD + s*8;
    float xv[8];
    *(float4*)&xv[0] = *(const float4*)xp;
    *(float4*)&xv[4] = *(const float4*)(xp+4);
    #pragma unroll
    for (int i=0;i<8;++i) x1[i] = xv[i] + XO[e][s*8+i];
    float sm = 0.f;
    #pragma unroll
    for (int i=0;i<8;++i) sm += x1[i];
    sm += __shfl_xor(sm,1); sm += __shfl_xor(sm,2);
    sm += __shfl_xor(sm,4); sm += __shfl_xor(sm,8);
    float mu = sm*(1.f/DD);
    float sq = 0.f;
    #pragma unroll
    for (int i=0;i<8;++i){ float d = x1[i]-mu; sq += d*d; }
    sq += __shfl_xor(sq,1); sq += __shfl_xor(sq,2);
    sq += __shfl_xor(sq,4); sq += __shfl_xor(sq,8);
    float rstd = rsqrtf(sq*(1.f/DD) + EPS);
    float4 w0 = *(const float4*)(lnw + s*8), w1 = *(const float4*)(lnw + s*8 + 4);
    float4 b0 = *(const float4*)(lnb + s*8), b1 = *(const float4*)(lnb + s*8 + 4);
    float wv[8] = {w0.x,w0.y,w0.z,w0.w,w1.x,w1.y,w1.z,w1.w};
    float bv[8] = {b0.x,b0.y,b0.z,b0.w,b1.x,b1.y,b1.z,b1.w};
    bf16x8 hb;
    #pragma unroll
    for (int i=0;i<8;++i) hb[i] = (__bf16)((x1[i]-mu)*rstd*wv[i] + bv[i]);
    __syncthreads();
    *(bf16x8*)(AB + swz128(e, s*16)) = hb;
  }
  __syncthreads();

  {
    const int f0w = w*128;
    f32x4 z = {0.f,0.f,0.f,0.f};
    f32x4 acc[8] = {z,z,z,z,z,z,z,z};
    #pragma unroll
    for (int k4=0;k4<4;++k4){
      bf16x8 a = *(const bf16x8*)(AB + swz128(lr, k4*64 + lg*16));
      #pragma unroll
      for (int nt=0;nt<8;++nt){
        bf16x8 b = *(const bf16x8*)(wib + (long)(f0w+nt*16+lr)*128 + k4*32 + lg*8);
        acc[nt] = MFMA(a, b, acc[nt]);
      }
    }
    #pragma unroll
    for (int nt=0;nt<8;++nt)
      #pragma unroll
      for (int r=0;r<4;++r){
        int e2 = lg*4 + r;
        int f = f0w + nt*16 + lr;
        float va = acc[nt][r];
        *(__bf16*)(IB + swz512(e2, f*2)) = (__bf16)fmaxf(va, 0.f);
      }
  }
  __syncthreads();

  {
    const int o0 = w*32;
    f32x4 z = {0.f,0.f,0.f,0.f};
    f32x4 acc[2] = {z,z};
    #pragma unroll
    for (int k16=0;k16<16;++k16){
      bf16x8 a = *(const bf16x8*)(IB + swz512(lr, k16*64 + lg*16));
      #pragma unroll
      for (int nt=0;nt<2;++nt){
        bf16x8 b = *(const bf16x8*)(wob + (long)(o0+nt*16+lr)*512 + k16*32 + lg*8);
        acc[nt] = MFMA(a, b, acc[nt]);
      }
    }
    #pragma unroll
    for (int nt=0;nt<2;++nt)
      #pragma unroll
      for (int r=0;r<4;++r)
        XO[lg*4+r][o0+nt*16+lr] = acc[nt][r];
  }
  __syncthreads();

  {
    float xn[8];
    #pragma unroll
    for (int i=0;i<8;++i) xn[i] = x1[i] + XO[e][s*8+i];
    float* xp = x + (long)(n0+e)*DD + s*8;
    *(float4*)xp = *(float4*)&xn[0];
    *(float4*)(xp+4) = *(float4*)&xn[4];
    bf16x8 hb;
    #pragma unroll
    for (int i=0;i<8;++i) hb[i] = (__bf16)xn[i];
    *(bf16x8*)(xb + (long)(n0+e)*DD + s*8) = hb;
  }
}

extern "C" void kernel_launch(void* const* d_in, const int* in_sizes, int n_in,
                              void* d_out, int out_size, void* d_ws, size_t ws_size,
                              hipStream_t stream) {
  const int* node_ids   = (const int*)d_in[0];
  const int* edge_index = (const int*)d_in[1];
  const int* edge_ids   = (const int*)d_in[2];
  const float* node_emb = (const float*)d_in[3];
  const float* edge_emb = (const float*)d_in[4];
  const float* ln_w   = (const float*)d_in[5];
  const float* ln_b   = (const float*)d_in[6];
  const float* q_w    = (const float*)d_in[7];
  const float* relA_w = (const float*)d_in[8];
  const float* relA_b = (const float*)d_in[9];
  const float* relB_w = (const float*)d_in[10];
  const float* relB_b = (const float*)d_in[11];
  const float* relG_w = (const float*)d_in[12];
  const float* relG_b = (const float*)d_in[13];
  const float* k_w    = (const float*)d_in[14];
  const float* v_w    = (const float*)d_in[15];
  const float* o_w    = (const float*)d_in[16];
  const float* ff_ln_w= (const float*)d_in[17];
  const float* ff_ln_b= (const float*)d_in[18];
  const float* wi_w   = (const float*)d_in[19];
  const float* wo_w   = (const float*)d_in[20];
  const int* src = edge_index;        // edge_index[0] = j (kv side)
  const int* dst = edge_index + EE;   // edge_index[1] = i (query side)

  float* ws = (float*)d_ws;
  float* x   = ws;  ws += (long)NN*DD;
  float* q   = ws;  ws += (long)NN*DD;
  float* denom = ws; ws += NN*HH;
  float* agg   = ws; ws += (long)NN*DD;
  float* EKf   = ws; ws += (long)LL*RELV*DD;
  int* hist   = (int*)ws; ws += NN;
  int* perm   = (int*)ws; ws += EE;
  ushort* xb  = (ushort*)ws; ws += (long)NN*DD/2;
  ushort* XAb = (ushort*)ws; ws += (long)NN*FFF/2;
  ushort* EAb = (ushort*)ws; ws += (long)LL*RELV*FFF/2;
  ushort* A1b = (ushort*)ws; ws += (long)LL*FFF*DD/2;
  ushort* Gwb = (ushort*)ws; ws += (long)LL*DD*FFF/2;
  ushort* Bwb = (ushort*)ws; ws += (long)LL*DD*FFF/2;
  ushort* Kwb = (ushort*)ws; ws += (long)LL*DD*DD/2;
  ushort* Vwb = (ushort*)ws; ws += (long)LL*DD*DD/2;
  ushort* Qwb = (ushort*)ws; ws += (long)LL*DD*DD/2;
  ushort* Owb = (ushort*)ws; ws += (long)LL*DD*DD/2;
  ushort* Wib = (ushort*)ws; ws += (long)LL*FFF*DD/2;
  ushort* Wob = (ushort*)ws; ws += (long)LL*DD*FFF/2;

  k_gx<<<NN, 128, 0, stream>>>(node_ids, node_emb, x, xb, hist);
  // dst-sort (once; reused by both layers)
  k_hist<<<(EE+255)/256, 256, 0, stream>>>(dst, hist);
  k_scan<<<1, 256, 0, stream>>>(hist, hist);   // in-place: hist becomes cursor
  k_scatter<<<(EE+255)/256, 256, 0, stream>>>(dst, hist, perm);
  // weight prep: 2x k_prep + 1x k_f2b4 + 2x k_ea (was 14 launches)
  for (int l=0; l<LL; ++l){
    k_prep<<<256, 256, 0, stream>>>(
        relG_w + (long)l*DD*FFF, relB_w + (long)l*DD*FFF,
        k_w + (long)l*DD*256,    v_w + (long)l*DD*DD,
        relA_w + (long)l*FFF*256,
        Gwb + (long)l*DD*FFF, Bwb + (long)l*DD*FFF,
        Kwb + (long)l*DD*DD,  Vwb + (long)l*DD*DD, A1b + (long)l*FFF*DD);
    k_ea<<<RELV, 256, 0, stream>>>(edge_emb, relA_w + (long)l*FFF*256, relA_b + (long)l*FFF,
                                   k_w + (long)l*DD*256, EAb + (long)l*RELV*FFF, EKf + (long)l*RELV*DD);
  }
  k_f2b4<<<512, 256, 0, stream>>>(q_w, o_w, wi_w, wo_w, Qwb, Owb, Wib, Wob);

  for (int l=0; l<LL; ++l){
    k_lnq_xa<<<NN/NT, 256, 0, stream>>>(x, ln_w + l*DD, ln_b + l*DD,
        Qwb + (long)l*DD*DD, A1b + (long)l*FFF*DD, q, XAb, agg, denom);
    k_edge<<<EE/BM, 512, 0, stream>>>(xb, XAb, EAb + (long)l*RELV*FFF, EKf + (long)l*RELV*DD,
        q, src, dst, edge_ids, perm,
        Gwb + (long)l*DD*FFF,  relG_b + (long)l*DD,
        Bwb + (long)l*DD*FFF,  relB_b + (long)l*DD,
        Kwb + (long)l*DD*DD,   Vwb + (long)l*DD*DD,
        agg, denom);
    k_node<<<NN/NT, 256, 0, stream>>>(agg, denom, Owb + (long)l*DD*DD,
        ff_ln_w + l*DD, ff_ln_b + l*DD,
        Wib + (long)l*FFF*DD, Wob + (long)l*DD*FFF, x, xb);
  }
  hipMemcpyAsync(d_out, x, (size_t)NN*DD*sizeof(float), hipMemcpyDeviceToDevice, stream);
}